// Round 6
// baseline (2509.815 us; speedup 1.0000x reference)
//
#include <hip/hip_runtime.h>

#define N_NODES 25600
#define N_EDGES 409600
#define BGR 128
#define EFE 1024
#define DIM 128
#define NLAYERS 8
#define KPOOL 32
#define NPG 200

typedef unsigned short ushort_t;
typedef __attribute__((ext_vector_type(8))) short bf16x8;
typedef __attribute__((ext_vector_type(4))) float f32x4;

#define STG_S 144  // per-wave C-staging stride (bf16 elems); 288B ≡ 8 dwords mod 32 banks

__device__ __forceinline__ float b2f(ushort_t v) {
    return __uint_as_float(((unsigned int)v) << 16);
}
__device__ __forceinline__ ushort_t f2b(float f) {
    unsigned int u = __float_as_uint(f);
    unsigned int r = (u + 0x7fffu + ((u >> 16) & 1u)) >> 16;
    return (ushort_t)r;
}
__device__ __forceinline__ uint2 pack4(float4 v) {
    uint2 p;
    p.x = (unsigned int)f2b(v.x) | ((unsigned int)f2b(v.y) << 16);
    p.y = (unsigned int)f2b(v.z) | ((unsigned int)f2b(v.w) << 16);
    return p;
}

// ---------------- W_fij -> fragment-linear bf16 ----------------
// Wf[((kc*8+nt)*64 + lane)*8 + j] = W[k][n],  k=kc*32+(lane>>4)*8+j, n=nt*16+(lane&15)
// (B-fragment indexing empirically verified in R4/R5: absmax 0.0)
__global__ void wfprep(const float* __restrict__ W, ushort_t* __restrict__ Wf) {
    int idx = blockIdx.x * 256 + threadIdx.x;  // 8 * 16384
    int l = idx >> 14, rem = idx & 16383;
    int j = rem & 7, lane = (rem >> 3) & 63, nt = (rem >> 9) & 7, kc = rem >> 12;
    int q = lane >> 4, r = lane & 15;
    int k = kc * 32 + q * 8 + j, n = nt * 16 + r;
    Wf[idx] = f2b(W[l * 16384 + k * 128 + n]);
}

// ---------------- zero deg ----------------
__global__ void zero_deg(int* __restrict__ deg, int n) {
    int i = blockIdx.x * 256 + threadIdx.x;
    if (i < n) deg[i] = 0;
}

// ---------------- CSR build ----------------
__global__ void count_deg(const int* __restrict__ dst, int* __restrict__ deg, int n) {
    int i = blockIdx.x * 256 + threadIdx.x;
    if (i < n) atomicAdd(&deg[dst[i]], 1);
}

__global__ __launch_bounds__(1024) void scan_kernel(const int* __restrict__ deg,
                                                    int* __restrict__ off,
                                                    int* __restrict__ cursor, int n) {
    __shared__ int buf[1024];
    __shared__ int carry;
    int t = threadIdx.x;
    if (t == 0) carry = 0;
    __syncthreads();
    for (int base = 0; base < n; base += 1024) {
        int v = (base + t < n) ? deg[base + t] : 0;
        buf[t] = v;
        __syncthreads();
        for (int s = 1; s < 1024; s <<= 1) {
            int x = (t >= s) ? buf[t - s] : 0;
            __syncthreads();
            buf[t] += x;
            __syncthreads();
        }
        int excl = buf[t] - v;
        if (base + t < n) { off[base + t] = carry + excl; cursor[base + t] = carry + excl; }
        __syncthreads();
        if (t == 1023) carry += buf[1023];
        __syncthreads();
    }
    if (t == 0) off[n] = carry;
}

__global__ void scatter_csr(const int* __restrict__ dst, int* __restrict__ cursor,
                            int* __restrict__ csr, int n) {
    int i = blockIdx.x * 256 + threadIdx.x;
    if (i < n) {
        int p = atomicAdd(&cursor[dst[i]], 1);
        csr[p] = i;
    }
}

// ---------------- init ----------------
__global__ void init_h(const int* __restrict__ tok, const float* __restrict__ emb,
                       float* __restrict__ h) {
    int i = blockIdx.x * 256 + threadIdx.x;
    int r = i >> 7, d = i & 127;
    float v = emb[tok[r] * DIM + d];
    h[i] = fmaxf(v, 0.f);
}

// eftab[t][d] = sum_k e_token_emb[t][k] * W_fij0[k][d]
__global__ __launch_bounds__(128) void eftab_kernel(const float* __restrict__ etab,
                                                    const float* __restrict__ W,
                                                    float* __restrict__ out) {
    int r = blockIdx.x, d = threadIdx.x;
    float acc = 0.f;
    for (int k = 0; k < DIM; k++)
        acc += etab[r * DIM + k] * W[k * DIM + d];
    out[r * DIM + d] = acc;
}

// ---------------- node GEMMs: A(fp32) @ W(fp32->bf16), OUTPUT bf16 ----------------
__global__ __launch_bounds__(256) void node_gemm3(
    const float* __restrict__ A,
    const float* __restrict__ W0, const float* __restrict__ W1,
    const float* __restrict__ W2,
    ushort_t* __restrict__ C0, ushort_t* __restrict__ C1, ushort_t* __restrict__ C2) {
    __shared__ float As[64 * 128];
    __shared__ uint2 Ws4[128 * 32];
    int tid = threadIdx.x;
    size_t row0 = (size_t)blockIdx.x * 64;
    const float4* Ag = (const float4*)(A + row0 * DIM);
    for (int f = tid; f < 64 * 32; f += 256) ((float4*)As)[f] = Ag[f];
    int cq = tid & 31, r0 = (tid >> 5) * 8;
    const float* Wlist[3] = {W0, W1, W2};
    ushort_t* Clist[3] = {C0, C1, C2};
    for (int m = 0; m < 3; m++) {
        __syncthreads();
        const float4* Wg = (const float4*)Wlist[m];
        for (int i = tid; i < 128 * 32; i += 256) Ws4[i] = pack4(Wg[i]);
        __syncthreads();
        float acc[8][4] = {};
        for (int k = 0; k < 128; k++) {
            uint2 wp = Ws4[k * 32 + cq];
            float w0 = __uint_as_float(wp.x << 16);
            float w1 = __uint_as_float(wp.x & 0xffff0000u);
            float w2 = __uint_as_float(wp.y << 16);
            float w3 = __uint_as_float(wp.y & 0xffff0000u);
#pragma unroll
            for (int i = 0; i < 8; i++) {
                float a = As[(r0 + i) * 128 + k];
                acc[i][0] += a * w0; acc[i][1] += a * w1;
                acc[i][2] += a * w2; acc[i][3] += a * w3;
            }
        }
        ushort_t* Cp = Clist[m];
#pragma unroll
        for (int i = 0; i < 8; i++) {
            *(uint2*)&Cp[(row0 + r0 + i) * DIM + cq * 4] =
                pack4(make_float4(acc[i][0], acc[i][1], acc[i][2], acc[i][3]));
        }
    }
}

// single-W with bias + relu (final Wf), fp32 in/out
__global__ __launch_bounds__(256) void node_gemm1(
    const float* __restrict__ A, const float* __restrict__ W,
    const float* __restrict__ bias, float* __restrict__ C) {
    __shared__ float As[64 * 128];
    __shared__ uint2 Ws4[128 * 32];
    int tid = threadIdx.x;
    size_t row0 = (size_t)blockIdx.x * 64;
    const float4* Ag = (const float4*)(A + row0 * DIM);
    for (int f = tid; f < 64 * 32; f += 256) ((float4*)As)[f] = Ag[f];
    const float4* Wg = (const float4*)W;
    for (int i = tid; i < 128 * 32; i += 256) Ws4[i] = pack4(Wg[i]);
    __syncthreads();
    int cq = tid & 31, r0 = (tid >> 5) * 8, c0 = cq * 4;
    float acc[8][4] = {};
    for (int k = 0; k < 128; k++) {
        uint2 wp = Ws4[k * 32 + cq];
        float w0 = __uint_as_float(wp.x << 16);
        float w1 = __uint_as_float(wp.x & 0xffff0000u);
        float w2 = __uint_as_float(wp.y << 16);
        float w3 = __uint_as_float(wp.y & 0xffff0000u);
#pragma unroll
        for (int i = 0; i < 8; i++) {
            float a = As[(r0 + i) * 128 + k];
            acc[i][0] += a * w0; acc[i][1] += a * w1;
            acc[i][2] += a * w2; acc[i][3] += a * w3;
        }
    }
    float b0 = bias[c0], b1 = bias[c0 + 1], b2v = bias[c0 + 2], b3v = bias[c0 + 3];
#pragma unroll
    for (int i = 0; i < 8; i++) {
        *(float4*)&C[(row0 + r0 + i) * DIM + c0] =
            make_float4(fmaxf(acc[i][0] + b0, 0.f), fmaxf(acc[i][1] + b1, 0.f),
                        fmaxf(acc[i][2] + b2v, 0.f), fmaxf(acc[i][3] + b3v, 0.f));
    }
}

// ---------------- MFMA edge GEMM (layers 1..7): barrier-free tile loop ----------------
// 1280 blocks x 5 tiles x 64 edges. W in LDS once (fragment-linear, 32 KB).
// A-fragments direct from global. Per-wave private C-staging slab -> NO __syncthreads
// after the initial W load (wave owns C rows 16wv..16wv+15; DS ops in-order per wave).
__global__ __launch_bounds__(256) void edge_gemm_mfma(
    ushort_t* __restrict__ e,
    const ushort_t* __restrict__ fni, const ushort_t* __restrict__ fnj,
    const int* __restrict__ src, const int* __restrict__ dst,
    const ushort_t* __restrict__ Wf,                 // fragment-linear bf16, 16384 elems
    const float* __restrict__ attn, const float* __restrict__ bias,
    float* __restrict__ score) {
    __shared__ __align__(16) ushort_t wF[16384];       // 32 KB
    __shared__ __align__(16) ushort_t stg[4][16 * STG_S];  // 4x4608 B = 18 KB

    int tid = threadIdx.x;
    // W fragments -> LDS (linear, coalesced)
    {
        const uint4* wg = (const uint4*)Wf;
        uint4* ws = (uint4*)wF;
        for (int i = tid; i < 2048; i += 256) ws[i] = wg[i];
    }
    __syncthreads();  // the only barrier

    int wv = tid >> 6, lane = tid & 63;
    int r = lane & 15, q = lane >> 4;
    int el = lane >> 2, qq = lane & 3;
    ushort_t* ss = &stg[wv][0];

    for (int t = 0; t < 5; t++) {
        size_t tile = (size_t)blockIdx.x * 5 + t;
        size_t row = tile * 64 + 16 * wv;

        // A fragments straight from global e
        const ushort_t* aRow = e + (row + r) * DIM + q * 8;
        bf16x8 a0 = *(const bf16x8*)(aRow);
        bf16x8 a1 = *(const bf16x8*)(aRow + 32);
        bf16x8 a2 = *(const bf16x8*)(aRow + 64);
        bf16x8 a3 = *(const bf16x8*)(aRow + 96);

        f32x4 acc[8] = {};
        const bf16x8* wfrag = (const bf16x8*)wF;  // [(kc*8+nt)*64 + lane]
#pragma unroll
        for (int nt = 0; nt < 8; nt++)
            acc[nt] = __builtin_amdgcn_mfma_f32_16x16x32_bf16(a0, wfrag[(0 * 8 + nt) * 64 + lane], acc[nt], 0, 0, 0);
#pragma unroll
        for (int nt = 0; nt < 8; nt++)
            acc[nt] = __builtin_amdgcn_mfma_f32_16x16x32_bf16(a1, wfrag[(1 * 8 + nt) * 64 + lane], acc[nt], 0, 0, 0);
#pragma unroll
        for (int nt = 0; nt < 8; nt++)
            acc[nt] = __builtin_amdgcn_mfma_f32_16x16x32_bf16(a2, wfrag[(2 * 8 + nt) * 64 + lane], acc[nt], 0, 0, 0);
#pragma unroll
        for (int nt = 0; nt < 8; nt++)
            acc[nt] = __builtin_amdgcn_mfma_f32_16x16x32_bf16(a3, wfrag[(3 * 8 + nt) * 64 + lane], acc[nt], 0, 0, 0);

        // wave-private C transpose: row(local) = q*4+rg, col = nt*16+r
#pragma unroll
        for (int nt = 0; nt < 8; nt++)
#pragma unroll
            for (int rg = 0; rg < 4; rg++)
                ss[(q * 4 + rg) * STG_S + nt * 16 + r] = f2b(acc[nt][rg]);

        // wave-private epilogue: 4 lanes/edge, 32 contiguous cols each
        size_t eid = row + el;
        int sv = src[eid], dv = dst[eid];
        const uint4* nip = (const uint4*)(fni + (size_t)sv * DIM + qq * 32);
        const uint4* njp = (const uint4*)(fnj + (size_t)dv * DIM + qq * 32);
        const uint4* sp = (const uint4*)(ss + el * STG_S + qq * 32);
        uint4 outv[4];
        float p = 0.f;
#pragma unroll
        for (int cc = 0; cc < 4; cc++) {
            uint4 avq = sp[cc];
            uint4 niq = nip[cc];
            uint4 njq = njp[cc];
#pragma unroll
            for (int u = 0; u < 4; u++) {
                unsigned int aw = ((const unsigned int*)&avq)[u];
                unsigned int nw = ((const unsigned int*)&niq)[u];
                unsigned int jw = ((const unsigned int*)&njq)[u];
                int c = qq * 32 + cc * 8 + u * 2;
                float v0 = __uint_as_float(aw << 16) + __uint_as_float(nw << 16) +
                           __uint_as_float(jw << 16) + bias[c];
                float v1 = __uint_as_float(aw & 0xffff0000u) + __uint_as_float(nw & 0xffff0000u) +
                           __uint_as_float(jw & 0xffff0000u) + bias[c + 1];
                v0 = v0 > 0.f ? v0 : 0.01f * v0;
                v1 = v1 > 0.f ? v1 : 0.01f * v1;
                ((unsigned int*)&outv[cc])[u] =
                    (unsigned int)f2b(v0) | ((unsigned int)f2b(v1) << 16);
                p += v0 * attn[c] + v1 * attn[c + 1];
            }
        }
        uint4* ep = (uint4*)(e + eid * DIM + qq * 32);
#pragma unroll
        for (int cc = 0; cc < 4; cc++) ep[cc] = outv[cc];
        p += __shfl_xor(p, 1);
        p += __shfl_xor(p, 2);
        if (qq == 0) score[eid] = p;
    }
}

// ---------------- layer-0 edge kernel (bf16 fni/fnj, bf16 e out) ----------------
__global__ __launch_bounds__(256) void edge0(
    const int* __restrict__ tokens_e, const float* __restrict__ eftab,
    const ushort_t* __restrict__ fni, const ushort_t* __restrict__ fnj,
    const int* __restrict__ src, const int* __restrict__ dst,
    const float* __restrict__ attn, const float* __restrict__ bias,
    ushort_t* __restrict__ e, float* __restrict__ score) {
    unsigned int gid = blockIdx.x * 256 + threadIdx.x;  // E*32 threads
    unsigned int eid = gid >> 5;
    int cq = gid & 31, c0 = cq * 4;
    int tok = tokens_e[eid];
    int sv = src[eid], dv = dst[eid];
    float4 t = *(const float4*)&eftab[tok * DIM + c0];
    uint2 niw = *(const uint2*)(fni + (size_t)sv * DIM + c0);
    uint2 njw = *(const uint2*)(fnj + (size_t)dv * DIM + c0);
    float ni0 = __uint_as_float(niw.x << 16), ni1 = __uint_as_float(niw.x & 0xffff0000u);
    float ni2 = __uint_as_float(niw.y << 16), ni3 = __uint_as_float(niw.y & 0xffff0000u);
    float nj0 = __uint_as_float(njw.x << 16), nj1 = __uint_as_float(njw.x & 0xffff0000u);
    float nj2 = __uint_as_float(njw.y << 16), nj3 = __uint_as_float(njw.y & 0xffff0000u);
    float v0 = t.x + ni0 + nj0 + bias[c0];
    float v1 = t.y + ni1 + nj1 + bias[c0 + 1];
    float v2 = t.z + ni2 + nj2 + bias[c0 + 2];
    float v3 = t.w + ni3 + nj3 + bias[c0 + 3];
    v0 = v0 > 0.f ? v0 : 0.01f * v0;
    v1 = v1 > 0.f ? v1 : 0.01f * v1;
    v2 = v2 > 0.f ? v2 : 0.01f * v2;
    v3 = v3 > 0.f ? v3 : 0.01f * v3;
    *(uint2*)(e + (size_t)eid * DIM + c0) = pack4(make_float4(v0, v1, v2, v3));
    float p = v0 * attn[c0] + v1 * attn[c0 + 1] + v2 * attn[c0 + 2] + v3 * attn[c0 + 3];
#pragma unroll
    for (int o = 1; o < 32; o <<= 1) p += __shfl_xor(p, o);
    if (cq == 0) score[eid] = p;
}

// ---------------- per-node softmax + weighted aggregation (bf16 hs) ----------------
__global__ __launch_bounds__(128) void agg_kernel(
    const int* __restrict__ off, const int* __restrict__ csr, const int* __restrict__ src,
    const float* __restrict__ score, const ushort_t* __restrict__ hs, float* __restrict__ h) {
    int n = blockIdx.x, t = threadIdx.x;
    int b0 = off[n], b1 = off[n + 1];
    int deg = b1 - b0;
    __shared__ float red[128];
    __shared__ float wgt[128];
    __shared__ int sidx[128];
    float m = -1e30f;
    for (int j = t; j < deg; j += 128) m = fmaxf(m, score[csr[b0 + j]]);
    red[t] = m;
    __syncthreads();
    for (int s = 64; s > 0; s >>= 1) { if (t < s) red[t] = fmaxf(red[t], red[t + s]); __syncthreads(); }
    m = red[0];
    __syncthreads();
    float se = 0.f;
    for (int j = t; j < deg; j += 128) se += __expf(score[csr[b0 + j]] - m);
    red[t] = se;
    __syncthreads();
    for (int s = 64; s > 0; s >>= 1) { if (t < s) red[t] += red[t + s]; __syncthreads(); }
    float inv = (deg > 0) ? 1.f / red[0] : 0.f;
    __syncthreads();
    float acc = 0.f;
    for (int base = 0; base < deg; base += 128) {
        int c = min(128, deg - base);
        if (t < c) {
            int eid = csr[b0 + base + t];
            wgt[t] = __expf(score[eid] - m) * inv;
            sidx[t] = src[eid];
        }
        __syncthreads();
        for (int i = 0; i < c; i++) acc += wgt[i] * b2f(hs[(size_t)sidx[i] * DIM + t]);
        __syncthreads();
    }
    h[(size_t)n * DIM + t] = fmaxf(acc, 0.f);
}

// ---------------- sort each node's 128 features ascending ----------------
__global__ __launch_bounds__(128) void sort_rows(const float* __restrict__ h2,
                                                 float* __restrict__ hsort,
                                                 float* __restrict__ maxval) {
    __shared__ float buf[128];
    int n = blockIdx.x, t = threadIdx.x;
    buf[t] = h2[(size_t)n * DIM + t];
    __syncthreads();
    for (int k = 2; k <= 128; k <<= 1) {
        for (int j = k >> 1; j > 0; j >>= 1) {
            int ixj = t ^ j;
            float a = buf[t], b = buf[ixj];
            __syncthreads();
            bool up = ((t & k) == 0);
            float mn = fminf(a, b), mx = fmaxf(a, b);
            buf[t] = up ? ((t < ixj) ? mn : mx) : ((t < ixj) ? mx : mn);
            __syncthreads();
        }
    }
    hsort[(size_t)n * DIM + t] = buf[t];
    if (t == 127) maxval[n] = buf[127];
}

// ---------------- per-graph top-k + gather pooled rows ----------------
__global__ __launch_bounds__(256) void topk_pool(const float* __restrict__ maxval,
                                                 const float* __restrict__ hsort,
                                                 float* __restrict__ pooled) {
    __shared__ float v[256];
    __shared__ int id[256];
    int b = blockIdx.x, t = threadIdx.x;
    v[t] = (t < NPG) ? maxval[b * NPG + t] : -1e30f;
    id[t] = t;
    __syncthreads();
    for (int k = 2; k <= 256; k <<= 1) {
        for (int j = k >> 1; j > 0; j >>= 1) {
            int ixj = t ^ j;
            float va = v[t], vb = v[ixj];
            int ia = id[t], ib = id[ixj];
            __syncthreads();
            bool dirDesc = ((t & k) == 0);
            bool cmp = (va > vb) || (va == vb && ia < ib);
            bool takeMine = ((t < ixj) == (dirDesc == cmp));
            v[t] = takeMine ? va : vb;
            id[t] = takeMine ? ia : ib;
            __syncthreads();
        }
    }
    for (int i = t; i < KPOOL * DIM; i += 256) {
        int kk = i >> 7, d = i & 127;
        pooled[((size_t)b * KPOOL + kk) * DIM + d] = hsort[((size_t)b * NPG + id[kk]) * DIM + d];
    }
}

// ---------------- ft = pooled @ W3 ; sl = ft@al3 ; sr = ft@ar3 ----------------
__global__ __launch_bounds__(128) void ft_kernel(
    const float* __restrict__ pooled, const float* __restrict__ W3,
    const float* __restrict__ al3, const float* __restrict__ ar3,
    float* __restrict__ ft, float* __restrict__ sl, float* __restrict__ sr) {
    __shared__ float ps[KPOOL * DIM];
    __shared__ float r1[128], r2[128];
    int b = blockIdx.x, d = threadIdx.x;
    for (int i = d; i < KPOOL * DIM; i += 128) ps[i] = pooled[(size_t)b * KPOOL * DIM + i];
    __syncthreads();
    float acc = 0.f;
    for (int k = 0; k < KPOOL * DIM; k++) acc += ps[k] * W3[(size_t)k * DIM + d];
    ft[b * DIM + d] = acc;
    r1[d] = acc * al3[d];
    r2[d] = acc * ar3[d];
    __syncthreads();
    for (int s = 64; s > 0; s >>= 1) {
        if (d < s) { r1[d] += r1[d + s]; r2[d] += r2[d + s]; }
        __syncthreads();
    }
    if (d == 0) { sl[b] = r1[0]; sr[b] = r2[0]; }
}

// ---------------- final-graph GAT ----------------
__global__ __launch_bounds__(128) void fg_kernel(
    const int* __restrict__ fg_src, const int* __restrict__ fg_dst,
    const float* __restrict__ sl, const float* __restrict__ sr,
    const float* __restrict__ ft, const float* __restrict__ b3,
    float* __restrict__ g) {
    __shared__ int list[EFE];
    __shared__ float wgt[EFE];
    __shared__ float red[128];
    __shared__ int cnt;
    int b = blockIdx.x, t = threadIdx.x;
    if (t == 0) cnt = 0;
    __syncthreads();
    for (int e = t; e < EFE; e += 128)
        if (fg_dst[e] == b) { int p = atomicAdd(&cnt, 1); list[p] = e; }
    __syncthreads();
    int deg = cnt;
    float srb = sr[b];
    float m = -1e30f;
    for (int j = t; j < deg; j += 128) {
        float s = sl[fg_src[list[j]]] + srb;
        s = s > 0.f ? s : 0.2f * s;
        m = fmaxf(m, s);
    }
    red[t] = m;
    __syncthreads();
    for (int s = 64; s > 0; s >>= 1) { if (t < s) red[t] = fmaxf(red[t], red[t + s]); __syncthreads(); }
    m = red[0];
    __syncthreads();
    float se = 0.f;
    for (int j = t; j < deg; j += 128) {
        float s = sl[fg_src[list[j]]] + srb;
        s = s > 0.f ? s : 0.2f * s;
        se += __expf(s - m);
    }
    red[t] = se;
    __syncthreads();
    for (int s = 64; s > 0; s >>= 1) { if (t < s) red[t] += red[t + s]; __syncthreads(); }
    float inv = (deg > 0) ? 1.f / red[0] : 0.f;
    __syncthreads();
    for (int j = t; j < deg; j += 128) {
        float s = sl[fg_src[list[j]]] + srb;
        s = s > 0.f ? s : 0.2f * s;
        wgt[j] = __expf(s - m) * inv;
    }
    __syncthreads();
    float acc = 0.f;
    for (int j = 0; j < deg; j++) acc += wgt[j] * ft[(size_t)fg_src[list[j]] * DIM + t];
    g[b * DIM + t] = fmaxf(acc + b3[t], 0.f);
}

// ---------------- g2 = relu(g @ Wl + bl) ----------------
__global__ __launch_bounds__(128) void gl_kernel(const float* __restrict__ g,
                                                 const float* __restrict__ Wl,
                                                 const float* __restrict__ bl,
                                                 float* __restrict__ g2) {
    __shared__ float gs[128];
    int b = blockIdx.x, d = threadIdx.x;
    gs[d] = g[b * DIM + d];
    __syncthreads();
    float acc = 0.f;
    for (int k = 0; k < 128; k++) acc += gs[k] * Wl[k * DIM + d];
    g2[b * DIM + d] = fmaxf(acc + bl[d], 0.f);
}

// ---------------- out = g2 @ Wc + bc ----------------
__global__ __launch_bounds__(256) void out_kernel(const float* __restrict__ g2,
                                                  const float* __restrict__ Wc,
                                                  const float* __restrict__ bc,
                                                  float* __restrict__ out) {
    int i = threadIdx.x;
    int b = i >> 1, j = i & 1;
    float acc = bc[j];
    for (int k = 0; k < 128; k++) acc += g2[b * DIM + k] * Wc[k * 2 + j];
    out[b * 2 + j] = acc;
}

extern "C" void kernel_launch(void* const* d_in, const int* in_sizes, int n_in,
                              void* d_out, int out_size, void* d_ws, size_t ws_size,
                              hipStream_t stream) {
    const int* tokens_h = (const int*)d_in[0];
    const int* tokens_e = (const int*)d_in[1];
    const int* src = (const int*)d_in[2];
    const int* dst = (const int*)d_in[3];
    const int* fg_src = (const int*)d_in[4];
    const int* fg_dst = (const int*)d_in[5];
    const float* token_emb = (const float*)d_in[6];
    const float* e_token_emb = (const float*)d_in[7];
    const float* W_ni = (const float*)d_in[8];
    const float* W_nj = (const float*)d_in[9];
    const float* W_fij = (const float*)d_in[10];
    const float* W_node = (const float*)d_in[11];
    const float* attn_e = (const float*)d_in[12];
    const float* bias_e = (const float*)d_in[13];
    const float* Wf = (const float*)d_in[14];
    const float* bf_ = (const float*)d_in[15];
    const float* W3 = (const float*)d_in[16];
    const float* al3 = (const float*)d_in[17];
    const float* ar3 = (const float*)d_in[18];
    const float* b3 = (const float*)d_in[19];
    const float* Wl = (const float*)d_in[20];
    const float* bl = (const float*)d_in[21];
    const float* Wc = (const float*)d_in[22];
    const float* bc = (const float*)d_in[23];
    float* out = (float*)d_out;

    char* w = (char*)d_ws;
    auto alloc = [&](size_t b) -> char* {
        char* p = w;
        w += (b + 255) & ~(size_t)255;
        return p;
    };
    float* h = (float*)alloc((size_t)N_NODES * DIM * 4);
    ushort_t* fni = (ushort_t*)alloc((size_t)N_NODES * DIM * 2);   // bf16
    ushort_t* fnj = (ushort_t*)alloc((size_t)N_NODES * DIM * 2);   // bf16
    ushort_t* hs = (ushort_t*)alloc((size_t)N_NODES * DIM * 2);    // bf16
    ushort_t* e = (ushort_t*)alloc((size_t)N_EDGES * DIM * 2);     // bf16
    float* score = (float*)alloc((size_t)N_EDGES * 4);
    int* deg = (int*)alloc((size_t)N_NODES * 4);
    int* off = (int*)alloc((size_t)(N_NODES + 1) * 4);
    int* cursor = (int*)alloc((size_t)N_NODES * 4);
    int* csr = (int*)alloc((size_t)N_EDGES * 4);
    float* eftab = (float*)alloc(100 * DIM * 4);
    float* maxval = (float*)alloc((size_t)N_NODES * 4);
    float* pooled = (float*)alloc((size_t)BGR * KPOOL * DIM * 4);
    float* ft = (float*)alloc(BGR * DIM * 4);
    float* sl = (float*)alloc(BGR * 4);
    float* sr = (float*)alloc(BGR * 4);
    float* g = (float*)alloc(BGR * DIM * 4);
    float* g2 = (float*)alloc(BGR * DIM * 4);
    ushort_t* Wf7 = (ushort_t*)alloc((size_t)NLAYERS * DIM * DIM * 2);
    // h2/hsort (fp32, 13.1 MB each) live in the dead e-region after the layer loop
    float* h2 = (float*)e;
    float* hsort = (float*)((char*)e + (size_t)16 * 1024 * 1024);

    // prep: fragment-linear bf16 W_fij
    wfprep<<<(NLAYERS * DIM * DIM) / 256, 256, 0, stream>>>(W_fij, Wf7);

    // CSR build
    zero_deg<<<(N_NODES + 255) / 256, 256, 0, stream>>>(deg, N_NODES);
    count_deg<<<N_EDGES / 256, 256, 0, stream>>>(dst, deg, N_EDGES);
    scan_kernel<<<1, 1024, 0, stream>>>(deg, off, cursor, N_NODES);
    scatter_csr<<<N_EDGES / 256, 256, 0, stream>>>(dst, cursor, csr, N_EDGES);

    init_h<<<(N_NODES * DIM) / 256, 256, 0, stream>>>(tokens_h, token_emb, h);
    eftab_kernel<<<100, 128, 0, stream>>>(e_token_emb, W_fij, eftab);

    for (int l = 0; l < NLAYERS; l++) {
        node_gemm3<<<N_NODES / 64, 256, 0, stream>>>(
            h, W_ni + l * DIM * DIM, W_nj + l * DIM * DIM, W_node + l * DIM * DIM,
            fni, fnj, hs);
        if (l == 0) {
            edge0<<<(N_EDGES * 32) / 256, 256, 0, stream>>>(
                tokens_e, eftab, fni, fnj, src, dst, attn_e, bias_e, e, score);
        } else {
            edge_gemm_mfma<<<1280, 256, 0, stream>>>(
                e, fni, fnj, src, dst, Wf7 + l * DIM * DIM,
                attn_e + l * DIM, bias_e + l * DIM, score);
        }
        agg_kernel<<<N_NODES, 128, 0, stream>>>(off, csr, src, score, hs, h);
    }

    node_gemm1<<<N_NODES / 64, 256, 0, stream>>>(h, Wf, bf_, h2);
    sort_rows<<<N_NODES, 128, 0, stream>>>(h2, hsort, maxval);
    topk_pool<<<BGR, 256, 0, stream>>>(maxval, hsort, pooled);
    ft_kernel<<<BGR, 128, 0, stream>>>(pooled, W3, al3, ar3, ft, sl, sr);
    fg_kernel<<<BGR, 128, 0, stream>>>(fg_src, fg_dst, sl, sr, ft, b3, g);
    gl_kernel<<<BGR, 128, 0, stream>>>(g, Wl, bl, g2);
    out_kernel<<<1, 256, 0, stream>>>(g2, Wc, bc, out);
}

// Round 7
// 1649.517 us; speedup vs baseline: 1.5215x; 1.5215x over previous
//
#include <hip/hip_runtime.h>

#define N_NODES 25600
#define N_EDGES 409600
#define BGR 128
#define EFE 1024
#define DIM 128
#define NLAYERS 8
#define KPOOL 32
#define NPG 200

typedef unsigned short ushort_t;
typedef __attribute__((ext_vector_type(8))) short bf16x8;
typedef __attribute__((ext_vector_type(4))) float f32x4;

#define STG_S 144  // per-wave C-staging stride (bf16 elems)

__device__ __forceinline__ float b2f(ushort_t v) {
    return __uint_as_float(((unsigned int)v) << 16);
}
__device__ __forceinline__ ushort_t f2b(float f) {
    unsigned int u = __float_as_uint(f);
    unsigned int r = (u + 0x7fffu + ((u >> 16) & 1u)) >> 16;
    return (ushort_t)r;
}
__device__ __forceinline__ uint2 pack4(float4 v) {
    uint2 p;
    p.x = (unsigned int)f2b(v.x) | ((unsigned int)f2b(v.y) << 16);
    p.y = (unsigned int)f2b(v.z) | ((unsigned int)f2b(v.w) << 16);
    return p;
}

// ---------------- W_fij -> fragment-linear bf16 (proven R6) ----------------
__global__ void wfprep(const float* __restrict__ W, ushort_t* __restrict__ Wf) {
    int idx = blockIdx.x * 256 + threadIdx.x;  // 8 * 16384
    int l = idx >> 14, rem = idx & 16383;
    int j = rem & 7, lane = (rem >> 3) & 63, nt = (rem >> 9) & 7, kc = rem >> 12;
    int q = lane >> 4, r = lane & 15;
    int k = kc * 32 + q * 8 + j, n = nt * 16 + r;
    Wf[idx] = f2b(W[l * 16384 + k * 128 + n]);
}

// W_ni / W_nj / W_node -> fragment-linear bf16, layout [m][l][16384]
__global__ void wnprep(const float* __restrict__ Wni, const float* __restrict__ Wnj,
                       const float* __restrict__ Wnode, ushort_t* __restrict__ Wn) {
    int idx = blockIdx.x * 256 + threadIdx.x;  // 3 * 8 * 16384
    int m = idx >> 17;
    int l = (idx >> 14) & 7;
    int rem = idx & 16383;
    int j = rem & 7, lane = (rem >> 3) & 63, nt = (rem >> 9) & 7, kc = rem >> 12;
    int q = lane >> 4, r = lane & 15;
    int k = kc * 32 + q * 8 + j, n = nt * 16 + r;
    const float* W = (m == 0) ? Wni : (m == 1) ? Wnj : Wnode;
    Wn[idx] = f2b(W[l * 16384 + k * 128 + n]);
}

// ---------------- zero deg ----------------
__global__ void zero_deg(int* __restrict__ deg, int n) {
    int i = blockIdx.x * 256 + threadIdx.x;
    if (i < n) deg[i] = 0;
}

// ---------------- CSR build ----------------
__global__ void count_deg(const int* __restrict__ dst, int* __restrict__ deg, int n) {
    int i = blockIdx.x * 256 + threadIdx.x;
    if (i < n) atomicAdd(&deg[dst[i]], 1);
}

__global__ __launch_bounds__(1024) void scan_kernel(const int* __restrict__ deg,
                                                    int* __restrict__ off,
                                                    int* __restrict__ cursor, int n) {
    __shared__ int buf[1024];
    __shared__ int carry;
    int t = threadIdx.x;
    if (t == 0) carry = 0;
    __syncthreads();
    for (int base = 0; base < n; base += 1024) {
        int v = (base + t < n) ? deg[base + t] : 0;
        buf[t] = v;
        __syncthreads();
        for (int s = 1; s < 1024; s <<= 1) {
            int x = (t >= s) ? buf[t - s] : 0;
            __syncthreads();
            buf[t] += x;
            __syncthreads();
        }
        int excl = buf[t] - v;
        if (base + t < n) { off[base + t] = carry + excl; cursor[base + t] = carry + excl; }
        __syncthreads();
        if (t == 1023) carry += buf[1023];
        __syncthreads();
    }
    if (t == 0) off[n] = carry;
}

__global__ void scatter_csr(const int* __restrict__ dst, int* __restrict__ cursor,
                            int* __restrict__ csr, int n) {
    int i = blockIdx.x * 256 + threadIdx.x;
    if (i < n) {
        int p = atomicAdd(&cursor[dst[i]], 1);
        csr[p] = i;
    }
}

// ---------------- init (h is bf16 now) ----------------
__global__ void init_h(const int* __restrict__ tok, const float* __restrict__ emb,
                       ushort_t* __restrict__ h) {
    int i = blockIdx.x * 256 + threadIdx.x;
    int r = i >> 7, d = i & 127;
    float v = emb[tok[r] * DIM + d];
    h[i] = f2b(fmaxf(v, 0.f));
}

// eftab[t][d] = sum_k e_token_emb[t][k] * W_fij0[k][d]
__global__ __launch_bounds__(128) void eftab_kernel(const float* __restrict__ etab,
                                                    const float* __restrict__ W,
                                                    float* __restrict__ out) {
    int r = blockIdx.x, d = threadIdx.x;
    float acc = 0.f;
    for (int k = 0; k < DIM; k++)
        acc += etab[r * DIM + k] * W[k * DIM + d];
    out[r * DIM + d] = acc;
}

// ---------------- MFMA node GEMM x3: h(bf16) @ W{ni,nj,node} -> fni,fnj,hs (bf16) ----------------
__global__ __launch_bounds__(256) void node_gemm3_mfma(
    const ushort_t* __restrict__ h,
    const ushort_t* __restrict__ Wm0, const ushort_t* __restrict__ Wm1,
    const ushort_t* __restrict__ Wm2,
    ushort_t* __restrict__ C0, ushort_t* __restrict__ C1, ushort_t* __restrict__ C2) {
    __shared__ __align__(16) ushort_t wF[16384];           // 32 KB
    __shared__ __align__(16) ushort_t stg[4][16 * STG_S];  // 18 KB
    int tid = threadIdx.x, wv = tid >> 6, lane = tid & 63;
    int r = lane & 15, q = lane >> 4;
    int el = lane >> 2, qq = lane & 3;
    size_t row = (size_t)blockIdx.x * 64 + 16 * wv;

    // A fragments from global h (held across all 3 weights)
    const ushort_t* aRow = h + (row + r) * DIM + q * 8;
    bf16x8 a0 = *(const bf16x8*)(aRow);
    bf16x8 a1 = *(const bf16x8*)(aRow + 32);
    bf16x8 a2 = *(const bf16x8*)(aRow + 64);
    bf16x8 a3 = *(const bf16x8*)(aRow + 96);

    const ushort_t* Wlist[3] = {Wm0, Wm1, Wm2};
    ushort_t* Clist[3] = {C0, C1, C2};
    ushort_t* ss = &stg[wv][0];
    for (int m = 0; m < 3; m++) {
        __syncthreads();  // wF safe to overwrite
        {
            const uint4* wg = (const uint4*)Wlist[m];
            uint4* ws = (uint4*)wF;
            for (int i = tid; i < 2048; i += 256) ws[i] = wg[i];
        }
        __syncthreads();
        f32x4 acc[8] = {};
        const bf16x8* wfrag = (const bf16x8*)wF;
#pragma unroll
        for (int nt = 0; nt < 8; nt++)
            acc[nt] = __builtin_amdgcn_mfma_f32_16x16x32_bf16(a0, wfrag[(0 * 8 + nt) * 64 + lane], acc[nt], 0, 0, 0);
#pragma unroll
        for (int nt = 0; nt < 8; nt++)
            acc[nt] = __builtin_amdgcn_mfma_f32_16x16x32_bf16(a1, wfrag[(1 * 8 + nt) * 64 + lane], acc[nt], 0, 0, 0);
#pragma unroll
        for (int nt = 0; nt < 8; nt++)
            acc[nt] = __builtin_amdgcn_mfma_f32_16x16x32_bf16(a2, wfrag[(2 * 8 + nt) * 64 + lane], acc[nt], 0, 0, 0);
#pragma unroll
        for (int nt = 0; nt < 8; nt++)
            acc[nt] = __builtin_amdgcn_mfma_f32_16x16x32_bf16(a3, wfrag[(3 * 8 + nt) * 64 + lane], acc[nt], 0, 0, 0);

        // wave-private transpose (no barrier: DS in-order per wave)
#pragma unroll
        for (int nt = 0; nt < 8; nt++)
#pragma unroll
            for (int rg = 0; rg < 4; rg++)
                ss[(q * 4 + rg) * STG_S + nt * 16 + r] = f2b(acc[nt][rg]);

        // write 16 rows x 256 B, 4 lanes/row x 64 B
        const uint4* sp = (const uint4*)(ss + el * STG_S + qq * 32);
        uint4* cp = (uint4*)(Clist[m] + (row + el) * DIM + qq * 32);
#pragma unroll
        for (int cc = 0; cc < 4; cc++) cp[cc] = sp[cc];
    }
}

// single-W with bias + relu (final Wf): h bf16 in, fp32 out
__global__ __launch_bounds__(256) void node_gemm1(
    const ushort_t* __restrict__ A, const float* __restrict__ W,
    const float* __restrict__ bias, float* __restrict__ C) {
    __shared__ float As[64 * 128];
    __shared__ uint2 Ws4[128 * 32];
    int tid = threadIdx.x;
    size_t row0 = (size_t)blockIdx.x * 64;
    const uint2* Ag = (const uint2*)(A + row0 * DIM);  // 4 bf16 per uint2
    for (int f = tid; f < 64 * 32; f += 256) {
        uint2 v = Ag[f];
        ((float4*)As)[f] = make_float4(
            __uint_as_float(v.x << 16), __uint_as_float(v.x & 0xffff0000u),
            __uint_as_float(v.y << 16), __uint_as_float(v.y & 0xffff0000u));
    }
    const float4* Wg = (const float4*)W;
    for (int i = tid; i < 128 * 32; i += 256) Ws4[i] = pack4(Wg[i]);
    __syncthreads();
    int cq = tid & 31, r0 = (tid >> 5) * 8, c0 = cq * 4;
    float acc[8][4] = {};
    for (int k = 0; k < 128; k++) {
        uint2 wp = Ws4[k * 32 + cq];
        float w0 = __uint_as_float(wp.x << 16);
        float w1 = __uint_as_float(wp.x & 0xffff0000u);
        float w2 = __uint_as_float(wp.y << 16);
        float w3 = __uint_as_float(wp.y & 0xffff0000u);
#pragma unroll
        for (int i = 0; i < 8; i++) {
            float a = As[(r0 + i) * 128 + k];
            acc[i][0] += a * w0; acc[i][1] += a * w1;
            acc[i][2] += a * w2; acc[i][3] += a * w3;
        }
    }
    float b0 = bias[c0], b1 = bias[c0 + 1], b2v = bias[c0 + 2], b3v = bias[c0 + 3];
#pragma unroll
    for (int i = 0; i < 8; i++) {
        *(float4*)&C[(row0 + r0 + i) * DIM + c0] =
            make_float4(fmaxf(acc[i][0] + b0, 0.f), fmaxf(acc[i][1] + b1, 0.f),
                        fmaxf(acc[i][2] + b2v, 0.f), fmaxf(acc[i][3] + b3v, 0.f));
    }
}

// ---------------- MFMA edge GEMM (unchanged from R6) ----------------
__global__ __launch_bounds__(256) void edge_gemm_mfma(
    ushort_t* __restrict__ e,
    const ushort_t* __restrict__ fni, const ushort_t* __restrict__ fnj,
    const int* __restrict__ src, const int* __restrict__ dst,
    const ushort_t* __restrict__ Wf,
    const float* __restrict__ attn, const float* __restrict__ bias,
    float* __restrict__ score) {
    __shared__ __align__(16) ushort_t wF[16384];
    __shared__ __align__(16) ushort_t stg[4][16 * STG_S];

    int tid = threadIdx.x;
    {
        const uint4* wg = (const uint4*)Wf;
        uint4* ws = (uint4*)wF;
        for (int i = tid; i < 2048; i += 256) ws[i] = wg[i];
    }
    __syncthreads();

    int wv = tid >> 6, lane = tid & 63;
    int r = lane & 15, q = lane >> 4;
    int el = lane >> 2, qq = lane & 3;
    ushort_t* ss = &stg[wv][0];

    for (int t = 0; t < 5; t++) {
        size_t tile = (size_t)blockIdx.x * 5 + t;
        size_t row = tile * 64 + 16 * wv;

        const ushort_t* aRow = e + (row + r) * DIM + q * 8;
        bf16x8 a0 = *(const bf16x8*)(aRow);
        bf16x8 a1 = *(const bf16x8*)(aRow + 32);
        bf16x8 a2 = *(const bf16x8*)(aRow + 64);
        bf16x8 a3 = *(const bf16x8*)(aRow + 96);

        f32x4 acc[8] = {};
        const bf16x8* wfrag = (const bf16x8*)wF;
#pragma unroll
        for (int nt = 0; nt < 8; nt++)
            acc[nt] = __builtin_amdgcn_mfma_f32_16x16x32_bf16(a0, wfrag[(0 * 8 + nt) * 64 + lane], acc[nt], 0, 0, 0);
#pragma unroll
        for (int nt = 0; nt < 8; nt++)
            acc[nt] = __builtin_amdgcn_mfma_f32_16x16x32_bf16(a1, wfrag[(1 * 8 + nt) * 64 + lane], acc[nt], 0, 0, 0);
#pragma unroll
        for (int nt = 0; nt < 8; nt++)
            acc[nt] = __builtin_amdgcn_mfma_f32_16x16x32_bf16(a2, wfrag[(2 * 8 + nt) * 64 + lane], acc[nt], 0, 0, 0);
#pragma unroll
        for (int nt = 0; nt < 8; nt++)
            acc[nt] = __builtin_amdgcn_mfma_f32_16x16x32_bf16(a3, wfrag[(3 * 8 + nt) * 64 + lane], acc[nt], 0, 0, 0);

#pragma unroll
        for (int nt = 0; nt < 8; nt++)
#pragma unroll
            for (int rg = 0; rg < 4; rg++)
                ss[(q * 4 + rg) * STG_S + nt * 16 + r] = f2b(acc[nt][rg]);

        size_t eid = row + el;
        int sv = src[eid], dv = dst[eid];
        const uint4* nip = (const uint4*)(fni + (size_t)sv * DIM + qq * 32);
        const uint4* njp = (const uint4*)(fnj + (size_t)dv * DIM + qq * 32);
        const uint4* sp = (const uint4*)(ss + el * STG_S + qq * 32);
        uint4 outv[4];
        float p = 0.f;
#pragma unroll
        for (int cc = 0; cc < 4; cc++) {
            uint4 avq = sp[cc];
            uint4 niq = nip[cc];
            uint4 njq = njp[cc];
#pragma unroll
            for (int u = 0; u < 4; u++) {
                unsigned int aw = ((const unsigned int*)&avq)[u];
                unsigned int nw = ((const unsigned int*)&niq)[u];
                unsigned int jw = ((const unsigned int*)&njq)[u];
                int c = qq * 32 + cc * 8 + u * 2;
                float v0 = __uint_as_float(aw << 16) + __uint_as_float(nw << 16) +
                           __uint_as_float(jw << 16) + bias[c];
                float v1 = __uint_as_float(aw & 0xffff0000u) + __uint_as_float(nw & 0xffff0000u) +
                           __uint_as_float(jw & 0xffff0000u) + bias[c + 1];
                v0 = v0 > 0.f ? v0 : 0.01f * v0;
                v1 = v1 > 0.f ? v1 : 0.01f * v1;
                ((unsigned int*)&outv[cc])[u] =
                    (unsigned int)f2b(v0) | ((unsigned int)f2b(v1) << 16);
                p += v0 * attn[c] + v1 * attn[c + 1];
            }
        }
        uint4* ep = (uint4*)(e + eid * DIM + qq * 32);
#pragma unroll
        for (int cc = 0; cc < 4; cc++) ep[cc] = outv[cc];
        p += __shfl_xor(p, 1);
        p += __shfl_xor(p, 2);
        if (qq == 0) score[eid] = p;
    }
}

// ---------------- layer-0 edge kernel ----------------
__global__ __launch_bounds__(256) void edge0(
    const int* __restrict__ tokens_e, const float* __restrict__ eftab,
    const ushort_t* __restrict__ fni, const ushort_t* __restrict__ fnj,
    const int* __restrict__ src, const int* __restrict__ dst,
    const float* __restrict__ attn, const float* __restrict__ bias,
    ushort_t* __restrict__ e, float* __restrict__ score) {
    unsigned int gid = blockIdx.x * 256 + threadIdx.x;
    unsigned int eid = gid >> 5;
    int cq = gid & 31, c0 = cq * 4;
    int tok = tokens_e[eid];
    int sv = src[eid], dv = dst[eid];
    float4 t = *(const float4*)&eftab[tok * DIM + c0];
    uint2 niw = *(const uint2*)(fni + (size_t)sv * DIM + c0);
    uint2 njw = *(const uint2*)(fnj + (size_t)dv * DIM + c0);
    float ni0 = __uint_as_float(niw.x << 16), ni1 = __uint_as_float(niw.x & 0xffff0000u);
    float ni2 = __uint_as_float(niw.y << 16), ni3 = __uint_as_float(niw.y & 0xffff0000u);
    float nj0 = __uint_as_float(njw.x << 16), nj1 = __uint_as_float(njw.x & 0xffff0000u);
    float nj2 = __uint_as_float(njw.y << 16), nj3 = __uint_as_float(njw.y & 0xffff0000u);
    float v0 = t.x + ni0 + nj0 + bias[c0];
    float v1 = t.y + ni1 + nj1 + bias[c0 + 1];
    float v2 = t.z + ni2 + nj2 + bias[c0 + 2];
    float v3 = t.w + ni3 + nj3 + bias[c0 + 3];
    v0 = v0 > 0.f ? v0 : 0.01f * v0;
    v1 = v1 > 0.f ? v1 : 0.01f * v1;
    v2 = v2 > 0.f ? v2 : 0.01f * v2;
    v3 = v3 > 0.f ? v3 : 0.01f * v3;
    *(uint2*)(e + (size_t)eid * DIM + c0) = pack4(make_float4(v0, v1, v2, v3));
    float p = v0 * attn[c0] + v1 * attn[c0 + 1] + v2 * attn[c0 + 2] + v3 * attn[c0 + 3];
#pragma unroll
    for (int o = 1; o < 32; o <<= 1) p += __shfl_xor(p, o);
    if (cq == 0) score[eid] = p;
}

// ---------------- per-node softmax + aggregation (bf16 hs, bf16 h out) ----------------
__global__ __launch_bounds__(128) void agg_kernel(
    const int* __restrict__ off, const int* __restrict__ csr, const int* __restrict__ src,
    const float* __restrict__ score, const ushort_t* __restrict__ hs,
    ushort_t* __restrict__ h) {
    int n = blockIdx.x, t = threadIdx.x;
    int b0 = off[n], b1 = off[n + 1];
    int deg = b1 - b0;
    __shared__ float red[128];
    __shared__ float wgt[128];
    __shared__ int sidx[128];
    float m = -1e30f;
    for (int j = t; j < deg; j += 128) m = fmaxf(m, score[csr[b0 + j]]);
    red[t] = m;
    __syncthreads();
    for (int s = 64; s > 0; s >>= 1) { if (t < s) red[t] = fmaxf(red[t], red[t + s]); __syncthreads(); }
    m = red[0];
    __syncthreads();
    float se = 0.f;
    for (int j = t; j < deg; j += 128) se += __expf(score[csr[b0 + j]] - m);
    red[t] = se;
    __syncthreads();
    for (int s = 64; s > 0; s >>= 1) { if (t < s) red[t] += red[t + s]; __syncthreads(); }
    float inv = (deg > 0) ? 1.f / red[0] : 0.f;
    __syncthreads();
    float acc = 0.f;
    for (int base = 0; base < deg; base += 128) {
        int c = min(128, deg - base);
        if (t < c) {
            int eid = csr[b0 + base + t];
            wgt[t] = __expf(score[eid] - m) * inv;
            sidx[t] = src[eid];
        }
        __syncthreads();
        for (int i = 0; i < c; i++) acc += wgt[i] * b2f(hs[(size_t)sidx[i] * DIM + t]);
        __syncthreads();
    }
    h[(size_t)n * DIM + t] = f2b(fmaxf(acc, 0.f));
}

// ---------------- sort each node's 128 features ascending ----------------
__global__ __launch_bounds__(128) void sort_rows(const float* __restrict__ h2,
                                                 float* __restrict__ hsort,
                                                 float* __restrict__ maxval) {
    __shared__ float buf[128];
    int n = blockIdx.x, t = threadIdx.x;
    buf[t] = h2[(size_t)n * DIM + t];
    __syncthreads();
    for (int k = 2; k <= 128; k <<= 1) {
        for (int j = k >> 1; j > 0; j >>= 1) {
            int ixj = t ^ j;
            float a = buf[t], b = buf[ixj];
            __syncthreads();
            bool up = ((t & k) == 0);
            float mn = fminf(a, b), mx = fmaxf(a, b);
            buf[t] = up ? ((t < ixj) ? mn : mx) : ((t < ixj) ? mx : mn);
            __syncthreads();
        }
    }
    hsort[(size_t)n * DIM + t] = buf[t];
    if (t == 127) maxval[n] = buf[127];
}

// ---------------- per-graph top-k + gather pooled rows ----------------
__global__ __launch_bounds__(256) void topk_pool(const float* __restrict__ maxval,
                                                 const float* __restrict__ hsort,
                                                 float* __restrict__ pooled) {
    __shared__ float v[256];
    __shared__ int id[256];
    int b = blockIdx.x, t = threadIdx.x;
    v[t] = (t < NPG) ? maxval[b * NPG + t] : -1e30f;
    id[t] = t;
    __syncthreads();
    for (int k = 2; k <= 256; k <<= 1) {
        for (int j = k >> 1; j > 0; j >>= 1) {
            int ixj = t ^ j;
            float va = v[t], vb = v[ixj];
            int ia = id[t], ib = id[ixj];
            __syncthreads();
            bool dirDesc = ((t & k) == 0);
            bool cmp = (va > vb) || (va == vb && ia < ib);
            bool takeMine = ((t < ixj) == (dirDesc == cmp));
            v[t] = takeMine ? va : vb;
            id[t] = takeMine ? ia : ib;
            __syncthreads();
        }
    }
    for (int i = t; i < KPOOL * DIM; i += 256) {
        int kk = i >> 7, d = i & 127;
        pooled[((size_t)b * KPOOL + kk) * DIM + d] = hsort[((size_t)b * NPG + id[kk]) * DIM + d];
    }
}

// ---------------- ft split-K: part[(b*8+s)][d] = sum over 512 k's ----------------
__global__ __launch_bounds__(256) void ft_partial(
    const float* __restrict__ pooled, const float* __restrict__ W3,
    float* __restrict__ part) {
    __shared__ float ps[512];
    __shared__ float red[256];
    int b = blockIdx.x, s = blockIdx.y;
    int t = threadIdx.x;
    int d = t & 127, half = t >> 7;
    for (int i = t; i < 512; i += 256) ps[i] = pooled[(size_t)b * 4096 + s * 512 + i];
    __syncthreads();
    float acc = 0.f;
    const float* Wp = W3 + (size_t)(s * 512 + half * 256) * DIM + d;
    const float* pp = ps + half * 256;
#pragma unroll 4
    for (int kk = 0; kk < 256; kk++) acc += pp[kk] * Wp[(size_t)kk * DIM];
    red[t] = acc;
    __syncthreads();
    if (t < 128) part[((size_t)b * 8 + s) * DIM + t] = red[t] + red[t + 128];
}

// reduce partials -> ft, sl, sr
__global__ __launch_bounds__(128) void ft_reduce(
    const float* __restrict__ part, const float* __restrict__ al3,
    const float* __restrict__ ar3, float* __restrict__ ft,
    float* __restrict__ sl, float* __restrict__ sr) {
    __shared__ float r1[128], r2[128];
    int b = blockIdx.x, d = threadIdx.x;
    float acc = 0.f;
#pragma unroll
    for (int s = 0; s < 8; s++) acc += part[((size_t)b * 8 + s) * DIM + d];
    ft[b * DIM + d] = acc;
    r1[d] = acc * al3[d];
    r2[d] = acc * ar3[d];
    __syncthreads();
    for (int s = 64; s > 0; s >>= 1) {
        if (d < s) { r1[d] += r1[d + s]; r2[d] += r2[d + s]; }
        __syncthreads();
    }
    if (d == 0) { sl[b] = r1[0]; sr[b] = r2[0]; }
}

// ---------------- final-graph GAT ----------------
__global__ __launch_bounds__(128) void fg_kernel(
    const int* __restrict__ fg_src, const int* __restrict__ fg_dst,
    const float* __restrict__ sl, const float* __restrict__ sr,
    const float* __restrict__ ft, const float* __restrict__ b3,
    float* __restrict__ g) {
    __shared__ int list[EFE];
    __shared__ float wgt[EFE];
    __shared__ float red[128];
    __shared__ int cnt;
    int b = blockIdx.x, t = threadIdx.x;
    if (t == 0) cnt = 0;
    __syncthreads();
    for (int e = t; e < EFE; e += 128)
        if (fg_dst[e] == b) { int p = atomicAdd(&cnt, 1); list[p] = e; }
    __syncthreads();
    int deg = cnt;
    float srb = sr[b];
    float m = -1e30f;
    for (int j = t; j < deg; j += 128) {
        float s = sl[fg_src[list[j]]] + srb;
        s = s > 0.f ? s : 0.2f * s;
        m = fmaxf(m, s);
    }
    red[t] = m;
    __syncthreads();
    for (int s = 64; s > 0; s >>= 1) { if (t < s) red[t] = fmaxf(red[t], red[t + s]); __syncthreads(); }
    m = red[0];
    __syncthreads();
    float se = 0.f;
    for (int j = t; j < deg; j += 128) {
        float s = sl[fg_src[list[j]]] + srb;
        s = s > 0.f ? s : 0.2f * s;
        se += __expf(s - m);
    }
    red[t] = se;
    __syncthreads();
    for (int s = 64; s > 0; s >>= 1) { if (t < s) red[t] += red[t + s]; __syncthreads(); }
    float inv = (deg > 0) ? 1.f / red[0] : 0.f;
    __syncthreads();
    for (int j = t; j < deg; j += 128) {
        float s = sl[fg_src[list[j]]] + srb;
        s = s > 0.f ? s : 0.2f * s;
        wgt[j] = __expf(s - m) * inv;
    }
    __syncthreads();
    float acc = 0.f;
    for (int j = 0; j < deg; j++) acc += wgt[j] * ft[(size_t)fg_src[list[j]] * DIM + t];
    g[b * DIM + t] = fmaxf(acc + b3[t], 0.f);
}

// ---------------- g2 = relu(g @ Wl + bl) ----------------
__global__ __launch_bounds__(128) void gl_kernel(const float* __restrict__ g,
                                                 const float* __restrict__ Wl,
                                                 const float* __restrict__ bl,
                                                 float* __restrict__ g2) {
    __shared__ float gs[128];
    int b = blockIdx.x, d = threadIdx.x;
    gs[d] = g[b * DIM + d];
    __syncthreads();
    float acc = 0.f;
    for (int k = 0; k < 128; k++) acc += gs[k] * Wl[k * DIM + d];
    g2[b * DIM + d] = fmaxf(acc + bl[d], 0.f);
}

// ---------------- out = g2 @ Wc + bc ----------------
__global__ __launch_bounds__(256) void out_kernel(const float* __restrict__ g2,
                                                  const float* __restrict__ Wc,
                                                  const float* __restrict__ bc,
                                                  float* __restrict__ out) {
    int i = threadIdx.x;
    int b = i >> 1, j = i & 1;
    float acc = bc[j];
    for (int k = 0; k < 128; k++) acc += g2[b * DIM + k] * Wc[k * 2 + j];
    out[b * 2 + j] = acc;
}

extern "C" void kernel_launch(void* const* d_in, const int* in_sizes, int n_in,
                              void* d_out, int out_size, void* d_ws, size_t ws_size,
                              hipStream_t stream) {
    const int* tokens_h = (const int*)d_in[0];
    const int* tokens_e = (const int*)d_in[1];
    const int* src = (const int*)d_in[2];
    const int* dst = (const int*)d_in[3];
    const int* fg_src = (const int*)d_in[4];
    const int* fg_dst = (const int*)d_in[5];
    const float* token_emb = (const float*)d_in[6];
    const float* e_token_emb = (const float*)d_in[7];
    const float* W_ni = (const float*)d_in[8];
    const float* W_nj = (const float*)d_in[9];
    const float* W_fij = (const float*)d_in[10];
    const float* W_node = (const float*)d_in[11];
    const float* attn_e = (const float*)d_in[12];
    const float* bias_e = (const float*)d_in[13];
    const float* Wf = (const float*)d_in[14];
    const float* bf_ = (const float*)d_in[15];
    const float* W3 = (const float*)d_in[16];
    const float* al3 = (const float*)d_in[17];
    const float* ar3 = (const float*)d_in[18];
    const float* b3 = (const float*)d_in[19];
    const float* Wl = (const float*)d_in[20];
    const float* bl = (const float*)d_in[21];
    const float* Wc = (const float*)d_in[22];
    const float* bc = (const float*)d_in[23];
    float* out = (float*)d_out;

    char* w = (char*)d_ws;
    auto alloc = [&](size_t b) -> char* {
        char* p = w;
        w += (b + 255) & ~(size_t)255;
        return p;
    };
    ushort_t* h = (ushort_t*)alloc((size_t)N_NODES * DIM * 2);     // bf16
    ushort_t* fni = (ushort_t*)alloc((size_t)N_NODES * DIM * 2);   // bf16
    ushort_t* fnj = (ushort_t*)alloc((size_t)N_NODES * DIM * 2);   // bf16
    ushort_t* hs = (ushort_t*)alloc((size_t)N_NODES * DIM * 2);    // bf16
    ushort_t* e = (ushort_t*)alloc((size_t)N_EDGES * DIM * 2);     // bf16
    float* score = (float*)alloc((size_t)N_EDGES * 4);
    int* deg = (int*)alloc((size_t)N_NODES * 4);
    int* off = (int*)alloc((size_t)(N_NODES + 1) * 4);
    int* cursor = (int*)alloc((size_t)N_NODES * 4);
    int* csr = (int*)alloc((size_t)N_EDGES * 4);
    float* eftab = (float*)alloc(100 * DIM * 4);
    float* maxval = (float*)alloc((size_t)N_NODES * 4);
    float* pooled = (float*)alloc((size_t)BGR * KPOOL * DIM * 4);
    float* ft = (float*)alloc(BGR * DIM * 4);
    float* part = (float*)alloc((size_t)BGR * 8 * DIM * 4);
    float* sl = (float*)alloc(BGR * 4);
    float* sr = (float*)alloc(BGR * 4);
    float* g = (float*)alloc(BGR * DIM * 4);
    float* g2 = (float*)alloc(BGR * DIM * 4);
    ushort_t* Wf7 = (ushort_t*)alloc((size_t)NLAYERS * DIM * DIM * 2);
    ushort_t* Wn = (ushort_t*)alloc((size_t)3 * NLAYERS * DIM * DIM * 2);
    // h2/hsort (fp32, 13.1 MB each) live in the dead e-region after the layer loop
    float* h2 = (float*)e;
    float* hsort = (float*)((char*)e + (size_t)16 * 1024 * 1024);

    // weight prep
    wfprep<<<(NLAYERS * DIM * DIM) / 256, 256, 0, stream>>>(W_fij, Wf7);
    wnprep<<<(3 * NLAYERS * DIM * DIM) / 256, 256, 0, stream>>>(W_ni, W_nj, W_node, Wn);

    // CSR build
    zero_deg<<<(N_NODES + 255) / 256, 256, 0, stream>>>(deg, N_NODES);
    count_deg<<<N_EDGES / 256, 256, 0, stream>>>(dst, deg, N_EDGES);
    scan_kernel<<<1, 1024, 0, stream>>>(deg, off, cursor, N_NODES);
    scatter_csr<<<N_EDGES / 256, 256, 0, stream>>>(dst, cursor, csr, N_EDGES);

    init_h<<<(N_NODES * DIM) / 256, 256, 0, stream>>>(tokens_h, token_emb, h);
    eftab_kernel<<<100, 128, 0, stream>>>(e_token_emb, W_fij, eftab);

    for (int l = 0; l < NLAYERS; l++) {
        node_gemm3_mfma<<<N_NODES / 64, 256, 0, stream>>>(
            h, Wn + (size_t)0 * NLAYERS * 16384 + l * 16384,
            Wn + (size_t)1 * NLAYERS * 16384 + l * 16384,
            Wn + (size_t)2 * NLAYERS * 16384 + l * 16384,
            fni, fnj, hs);
        if (l == 0) {
            edge0<<<(N_EDGES * 32) / 256, 256, 0, stream>>>(
                tokens_e, eftab, fni, fnj, src, dst, attn_e, bias_e, e, score);
        } else {
            edge_gemm_mfma<<<1280, 256, 0, stream>>>(
                e, fni, fnj, src, dst, Wf7 + l * DIM * DIM,
                attn_e + l * DIM, bias_e + l * DIM, score);
        }
        agg_kernel<<<N_NODES, 128, 0, stream>>>(off, csr, src, score, hs, h);
    }

    node_gemm1<<<N_NODES / 64, 256, 0, stream>>>(h, Wf, bf_, h2);
    sort_rows<<<N_NODES, 128, 0, stream>>>(h2, hsort, maxval);
    topk_pool<<<BGR, 256, 0, stream>>>(maxval, hsort, pooled);
    ft_partial<<<dim3(BGR, 8), 256, 0, stream>>>(pooled, W3, part);
    ft_reduce<<<BGR, 128, 0, stream>>>(part, al3, ar3, ft, sl, sr);
    fg_kernel<<<BGR, 128, 0, stream>>>(fg_src, fg_dst, sl, sr, ft, b3, g);
    gl_kernel<<<BGR, 128, 0, stream>>>(g, Wl, bl, g2);
    out_kernel<<<1, 256, 0, stream>>>(g2, Wc, bc, out);
}

// Round 8
// 1491.914 us; speedup vs baseline: 1.6823x; 1.1056x over previous
//
#include <hip/hip_runtime.h>

#define N_NODES 25600
#define N_EDGES 409600
#define BGR 128
#define EFE 1024
#define DIM 128
#define NLAYERS 8
#define KPOOL 32
#define NPG 200

typedef unsigned short ushort_t;
typedef __attribute__((ext_vector_type(8))) short bf16x8;
typedef __attribute__((ext_vector_type(4))) float f32x4;

#define STG_S 144  // per-wave C-staging stride (bf16 elems)

__device__ __forceinline__ float b2f(ushort_t v) {
    return __uint_as_float(((unsigned int)v) << 16);
}
__device__ __forceinline__ ushort_t f2b(float f) {
    unsigned int u = __float_as_uint(f);
    unsigned int r = (u + 0x7fffu + ((u >> 16) & 1u)) >> 16;
    return (ushort_t)r;
}
__device__ __forceinline__ uint2 pack4(float4 v) {
    uint2 p;
    p.x = (unsigned int)f2b(v.x) | ((unsigned int)f2b(v.y) << 16);
    p.y = (unsigned int)f2b(v.z) | ((unsigned int)f2b(v.w) << 16);
    return p;
}

// ---------------- W_fij -> fragment-linear bf16 (proven R6) ----------------
__global__ void wfprep(const float* __restrict__ W, ushort_t* __restrict__ Wf) {
    int idx = blockIdx.x * 256 + threadIdx.x;  // 8 * 16384
    int l = idx >> 14, rem = idx & 16383;
    int j = rem & 7, lane = (rem >> 3) & 63, nt = (rem >> 9) & 7, kc = rem >> 12;
    int q = lane >> 4, r = lane & 15;
    int k = kc * 32 + q * 8 + j, n = nt * 16 + r;
    Wf[idx] = f2b(W[l * 16384 + k * 128 + n]);
}

// W_ni / W_nj / W_node -> fragment-linear bf16, layout [m][l][16384]
__global__ void wnprep(const float* __restrict__ Wni, const float* __restrict__ Wnj,
                       const float* __restrict__ Wnode, ushort_t* __restrict__ Wn) {
    int idx = blockIdx.x * 256 + threadIdx.x;  // 3 * 8 * 16384
    int m = idx >> 17;
    int l = (idx >> 14) & 7;
    int rem = idx & 16383;
    int j = rem & 7, lane = (rem >> 3) & 63, nt = (rem >> 9) & 7, kc = rem >> 12;
    int q = lane >> 4, r = lane & 15;
    int k = kc * 32 + q * 8 + j, n = nt * 16 + r;
    const float* W = (m == 0) ? Wni : (m == 1) ? Wnj : Wnode;
    Wn[idx] = f2b(W[l * 16384 + k * 128 + n]);
}

// ---------------- zero deg ----------------
__global__ void zero_deg(int* __restrict__ deg, int n) {
    int i = blockIdx.x * 256 + threadIdx.x;
    if (i < n) deg[i] = 0;
}

// ---------------- CSR build ----------------
__global__ void count_deg(const int* __restrict__ dst, int* __restrict__ deg, int n) {
    int i = blockIdx.x * 256 + threadIdx.x;
    if (i < n) atomicAdd(&deg[dst[i]], 1);
}

__global__ __launch_bounds__(1024) void scan_kernel(const int* __restrict__ deg,
                                                    int* __restrict__ off,
                                                    int* __restrict__ cursor, int n) {
    __shared__ int buf[1024];
    __shared__ int carry;
    int t = threadIdx.x;
    if (t == 0) carry = 0;
    __syncthreads();
    for (int base = 0; base < n; base += 1024) {
        int v = (base + t < n) ? deg[base + t] : 0;
        buf[t] = v;
        __syncthreads();
        for (int s = 1; s < 1024; s <<= 1) {
            int x = (t >= s) ? buf[t - s] : 0;
            __syncthreads();
            buf[t] += x;
            __syncthreads();
        }
        int excl = buf[t] - v;
        if (base + t < n) { off[base + t] = carry + excl; cursor[base + t] = carry + excl; }
        __syncthreads();
        if (t == 1023) carry += buf[1023];
        __syncthreads();
    }
    if (t == 0) off[n] = carry;
}

__global__ void scatter_csr(const int* __restrict__ dst, int* __restrict__ cursor,
                            int* __restrict__ csr, int n) {
    int i = blockIdx.x * 256 + threadIdx.x;
    if (i < n) {
        int p = atomicAdd(&cursor[dst[i]], 1);
        csr[p] = i;
    }
}

// ---------------- init (h bf16) ----------------
__global__ void init_h(const int* __restrict__ tok, const float* __restrict__ emb,
                       ushort_t* __restrict__ h) {
    int i = blockIdx.x * 256 + threadIdx.x;
    int r = i >> 7, d = i & 127;
    float v = emb[tok[r] * DIM + d];
    h[i] = f2b(fmaxf(v, 0.f));
}

// eftab[t][d] = sum_k e_token_emb[t][k] * W_fij0[k][d]
__global__ __launch_bounds__(128) void eftab_kernel(const float* __restrict__ etab,
                                                    const float* __restrict__ W,
                                                    float* __restrict__ out) {
    int r = blockIdx.x, d = threadIdx.x;
    float acc = 0.f;
    for (int k = 0; k < DIM; k++)
        acc += etab[r * DIM + k] * W[k * DIM + d];
    out[r * DIM + d] = acc;
}

// ---------------- MFMA node GEMM: grid (400, 3); one W matrix per block ----------------
// LDS: wF 32 KB, staging overlays wF after barrier.
__global__ __launch_bounds__(256, 4) void node_gemm_mfma(
    const ushort_t* __restrict__ h,
    const ushort_t* __restrict__ Wn,   // [m][l=fixed][16384] base for this layer
    ushort_t* __restrict__ C0, ushort_t* __restrict__ C1, ushort_t* __restrict__ C2) {
    __shared__ __align__(16) ushort_t wF[16384];  // 32 KB; stg overlays
    int tid = threadIdx.x, wv = tid >> 6, lane = tid & 63;
    int r = lane & 15, q = lane >> 4;
    int el = lane >> 2, qq = lane & 3;
    int m = blockIdx.y;
    size_t row = (size_t)blockIdx.x * 64 + 16 * wv;

    {
        const uint4* wg = (const uint4*)(Wn + (size_t)m * NLAYERS * 16384);
        uint4* ws = (uint4*)wF;
        for (int i = tid; i < 2048; i += 256) ws[i] = wg[i];
    }
    __syncthreads();

    const ushort_t* aRow = h + (row + r) * DIM + q * 8;
    bf16x8 a0 = *(const bf16x8*)(aRow);
    bf16x8 a1 = *(const bf16x8*)(aRow + 32);
    bf16x8 a2 = *(const bf16x8*)(aRow + 64);
    bf16x8 a3 = *(const bf16x8*)(aRow + 96);

    f32x4 acc[8] = {};
    const bf16x8* wfrag = (const bf16x8*)wF;
#pragma unroll
    for (int nt = 0; nt < 8; nt++)
        acc[nt] = __builtin_amdgcn_mfma_f32_16x16x32_bf16(a0, wfrag[(0 * 8 + nt) * 64 + lane], acc[nt], 0, 0, 0);
#pragma unroll
    for (int nt = 0; nt < 8; nt++)
        acc[nt] = __builtin_amdgcn_mfma_f32_16x16x32_bf16(a1, wfrag[(1 * 8 + nt) * 64 + lane], acc[nt], 0, 0, 0);
#pragma unroll
    for (int nt = 0; nt < 8; nt++)
        acc[nt] = __builtin_amdgcn_mfma_f32_16x16x32_bf16(a2, wfrag[(2 * 8 + nt) * 64 + lane], acc[nt], 0, 0, 0);
#pragma unroll
    for (int nt = 0; nt < 8; nt++)
        acc[nt] = __builtin_amdgcn_mfma_f32_16x16x32_bf16(a3, wfrag[(3 * 8 + nt) * 64 + lane], acc[nt], 0, 0, 0);
    __syncthreads();  // all wF reads complete -> overlay with staging

    ushort_t* ss = wF + wv * 16 * STG_S;  // 4 x 4608 B = 18432 B < 32 KB
#pragma unroll
    for (int nt = 0; nt < 8; nt++)
#pragma unroll
        for (int rg = 0; rg < 4; rg++)
            ss[(q * 4 + rg) * STG_S + nt * 16 + r] = f2b(acc[nt][rg]);

    ushort_t* Cp = (m == 0) ? C0 : (m == 1) ? C1 : C2;
    const uint4* sp = (const uint4*)(ss + el * STG_S + qq * 32);
    uint4* cp = (uint4*)(Cp + (row + el) * DIM + qq * 32);
#pragma unroll
    for (int cc = 0; cc < 4; cc++) cp[cc] = sp[cc];
}

// single-W with bias + relu (final Wf): h bf16 in, fp32 out
__global__ __launch_bounds__(256) void node_gemm1(
    const ushort_t* __restrict__ A, const float* __restrict__ W,
    const float* __restrict__ bias, float* __restrict__ C) {
    __shared__ float As[64 * 128];
    __shared__ uint2 Ws4[128 * 32];
    int tid = threadIdx.x;
    size_t row0 = (size_t)blockIdx.x * 64;
    const uint2* Ag = (const uint2*)(A + row0 * DIM);
    for (int f = tid; f < 64 * 32; f += 256) {
        uint2 v = Ag[f];
        ((float4*)As)[f] = make_float4(
            __uint_as_float(v.x << 16), __uint_as_float(v.x & 0xffff0000u),
            __uint_as_float(v.y << 16), __uint_as_float(v.y & 0xffff0000u));
    }
    const float4* Wg = (const float4*)W;
    for (int i = tid; i < 128 * 32; i += 256) Ws4[i] = pack4(Wg[i]);
    __syncthreads();
    int cq = tid & 31, r0 = (tid >> 5) * 8, c0 = cq * 4;
    float acc[8][4] = {};
    for (int k = 0; k < 128; k++) {
        uint2 wp = Ws4[k * 32 + cq];
        float w0 = __uint_as_float(wp.x << 16);
        float w1 = __uint_as_float(wp.x & 0xffff0000u);
        float w2 = __uint_as_float(wp.y << 16);
        float w3 = __uint_as_float(wp.y & 0xffff0000u);
#pragma unroll
        for (int i = 0; i < 8; i++) {
            float a = As[(r0 + i) * 128 + k];
            acc[i][0] += a * w0; acc[i][1] += a * w1;
            acc[i][2] += a * w2; acc[i][3] += a * w3;
        }
    }
    float b0 = bias[c0], b1 = bias[c0 + 1], b2v = bias[c0 + 2], b3v = bias[c0 + 3];
#pragma unroll
    for (int i = 0; i < 8; i++) {
        *(float4*)&C[(row0 + r0 + i) * DIM + c0] =
            make_float4(fmaxf(acc[i][0] + b0, 0.f), fmaxf(acc[i][1] + b1, 0.f),
                        fmaxf(acc[i][2] + b2v, 0.f), fmaxf(acc[i][3] + b3v, 0.f));
    }
}

// ---------------- MFMA edge GEMM: 1 tile/block, 6400 blocks, 32 KB LDS ----------------
__global__ __launch_bounds__(256, 4) void edge_gemm_mfma(
    ushort_t* __restrict__ e,
    const ushort_t* __restrict__ fni, const ushort_t* __restrict__ fnj,
    const int* __restrict__ src, const int* __restrict__ dst,
    const ushort_t* __restrict__ Wf,
    const float* __restrict__ attn, const float* __restrict__ bias,
    float* __restrict__ score) {
    __shared__ __align__(16) ushort_t wF[16384];  // 32 KB; stg overlays after barrier

    int tid = threadIdx.x;
    {
        const uint4* wg = (const uint4*)Wf;
        uint4* ws = (uint4*)wF;
        for (int i = tid; i < 2048; i += 256) ws[i] = wg[i];
    }
    __syncthreads();

    int wv = tid >> 6, lane = tid & 63;
    int r = lane & 15, q = lane >> 4;
    int el = lane >> 2, qq = lane & 3;
    size_t row = (size_t)blockIdx.x * 64 + 16 * wv;

    const ushort_t* aRow = e + (row + r) * DIM + q * 8;
    bf16x8 a0 = *(const bf16x8*)(aRow);
    bf16x8 a1 = *(const bf16x8*)(aRow + 32);
    bf16x8 a2 = *(const bf16x8*)(aRow + 64);
    bf16x8 a3 = *(const bf16x8*)(aRow + 96);

    f32x4 acc[8] = {};
    const bf16x8* wfrag = (const bf16x8*)wF;
#pragma unroll
    for (int nt = 0; nt < 8; nt++)
        acc[nt] = __builtin_amdgcn_mfma_f32_16x16x32_bf16(a0, wfrag[(0 * 8 + nt) * 64 + lane], acc[nt], 0, 0, 0);
#pragma unroll
    for (int nt = 0; nt < 8; nt++)
        acc[nt] = __builtin_amdgcn_mfma_f32_16x16x32_bf16(a1, wfrag[(1 * 8 + nt) * 64 + lane], acc[nt], 0, 0, 0);
#pragma unroll
    for (int nt = 0; nt < 8; nt++)
        acc[nt] = __builtin_amdgcn_mfma_f32_16x16x32_bf16(a2, wfrag[(2 * 8 + nt) * 64 + lane], acc[nt], 0, 0, 0);
#pragma unroll
    for (int nt = 0; nt < 8; nt++)
        acc[nt] = __builtin_amdgcn_mfma_f32_16x16x32_bf16(a3, wfrag[(3 * 8 + nt) * 64 + lane], acc[nt], 0, 0, 0);
    __syncthreads();  // all wF reads complete -> overlay with wave-private staging

    ushort_t* ss = wF + wv * 16 * STG_S;
#pragma unroll
    for (int nt = 0; nt < 8; nt++)
#pragma unroll
        for (int rg = 0; rg < 4; rg++)
            ss[(q * 4 + rg) * STG_S + nt * 16 + r] = f2b(acc[nt][rg]);

    size_t eid = row + el;
    int sv = src[eid], dv = dst[eid];
    const uint4* nip = (const uint4*)(fni + (size_t)sv * DIM + qq * 32);
    const uint4* njp = (const uint4*)(fnj + (size_t)dv * DIM + qq * 32);
    const uint4* sp = (const uint4*)(ss + el * STG_S + qq * 32);
    uint4 outv[4];
    float p = 0.f;
#pragma unroll
    for (int cc = 0; cc < 4; cc++) {
        uint4 avq = sp[cc];
        uint4 niq = nip[cc];
        uint4 njq = njp[cc];
#pragma unroll
        for (int u = 0; u < 4; u++) {
            unsigned int aw = ((const unsigned int*)&avq)[u];
            unsigned int nw = ((const unsigned int*)&niq)[u];
            unsigned int jw = ((const unsigned int*)&njq)[u];
            int c = qq * 32 + cc * 8 + u * 2;
            float v0 = __uint_as_float(aw << 16) + __uint_as_float(nw << 16) +
                       __uint_as_float(jw << 16) + bias[c];
            float v1 = __uint_as_float(aw & 0xffff0000u) + __uint_as_float(nw & 0xffff0000u) +
                       __uint_as_float(jw & 0xffff0000u) + bias[c + 1];
            v0 = v0 > 0.f ? v0 : 0.01f * v0;
            v1 = v1 > 0.f ? v1 : 0.01f * v1;
            ((unsigned int*)&outv[cc])[u] =
                (unsigned int)f2b(v0) | ((unsigned int)f2b(v1) << 16);
            p += v0 * attn[c] + v1 * attn[c + 1];
        }
    }
    uint4* ep = (uint4*)(e + eid * DIM + qq * 32);
#pragma unroll
    for (int cc = 0; cc < 4; cc++) ep[cc] = outv[cc];
    p += __shfl_xor(p, 1);
    p += __shfl_xor(p, 2);
    if (qq == 0) score[eid] = p;
}

// ---------------- layer-0 edge kernel ----------------
__global__ __launch_bounds__(256) void edge0(
    const int* __restrict__ tokens_e, const float* __restrict__ eftab,
    const ushort_t* __restrict__ fni, const ushort_t* __restrict__ fnj,
    const int* __restrict__ src, const int* __restrict__ dst,
    const float* __restrict__ attn, const float* __restrict__ bias,
    ushort_t* __restrict__ e, float* __restrict__ score) {
    unsigned int gid = blockIdx.x * 256 + threadIdx.x;
    unsigned int eid = gid >> 5;
    int cq = gid & 31, c0 = cq * 4;
    int tok = tokens_e[eid];
    int sv = src[eid], dv = dst[eid];
    float4 t = *(const float4*)&eftab[tok * DIM + c0];
    uint2 niw = *(const uint2*)(fni + (size_t)sv * DIM + c0);
    uint2 njw = *(const uint2*)(fnj + (size_t)dv * DIM + c0);
    float ni0 = __uint_as_float(niw.x << 16), ni1 = __uint_as_float(niw.x & 0xffff0000u);
    float ni2 = __uint_as_float(niw.y << 16), ni3 = __uint_as_float(niw.y & 0xffff0000u);
    float nj0 = __uint_as_float(njw.x << 16), nj1 = __uint_as_float(njw.x & 0xffff0000u);
    float nj2 = __uint_as_float(njw.y << 16), nj3 = __uint_as_float(njw.y & 0xffff0000u);
    float v0 = t.x + ni0 + nj0 + bias[c0];
    float v1 = t.y + ni1 + nj1 + bias[c0 + 1];
    float v2 = t.z + ni2 + nj2 + bias[c0 + 2];
    float v3 = t.w + ni3 + nj3 + bias[c0 + 3];
    v0 = v0 > 0.f ? v0 : 0.01f * v0;
    v1 = v1 > 0.f ? v1 : 0.01f * v1;
    v2 = v2 > 0.f ? v2 : 0.01f * v2;
    v3 = v3 > 0.f ? v3 : 0.01f * v3;
    *(uint2*)(e + (size_t)eid * DIM + c0) = pack4(make_float4(v0, v1, v2, v3));
    float p = v0 * attn[c0] + v1 * attn[c0 + 1] + v2 * attn[c0 + 2] + v3 * attn[c0 + 3];
#pragma unroll
    for (int o = 1; o < 32; o <<= 1) p += __shfl_xor(p, o);
    if (cq == 0) score[eid] = p;
}

// ---------------- per-node softmax + aggregation (bf16 hs, bf16 h out) ----------------
__global__ __launch_bounds__(128) void agg_kernel(
    const int* __restrict__ off, const int* __restrict__ csr, const int* __restrict__ src,
    const float* __restrict__ score, const ushort_t* __restrict__ hs,
    ushort_t* __restrict__ h) {
    int n = blockIdx.x, t = threadIdx.x;
    int b0 = off[n], b1 = off[n + 1];
    int deg = b1 - b0;
    __shared__ float red[128];
    __shared__ float wgt[128];
    __shared__ int sidx[128];
    float m = -1e30f;
    for (int j = t; j < deg; j += 128) m = fmaxf(m, score[csr[b0 + j]]);
    red[t] = m;
    __syncthreads();
    for (int s = 64; s > 0; s >>= 1) { if (t < s) red[t] = fmaxf(red[t], red[t + s]); __syncthreads(); }
    m = red[0];
    __syncthreads();
    float se = 0.f;
    for (int j = t; j < deg; j += 128) se += __expf(score[csr[b0 + j]] - m);
    red[t] = se;
    __syncthreads();
    for (int s = 64; s > 0; s >>= 1) { if (t < s) red[t] += red[t + s]; __syncthreads(); }
    float inv = (deg > 0) ? 1.f / red[0] : 0.f;
    __syncthreads();
    float acc = 0.f;
    for (int base = 0; base < deg; base += 128) {
        int c = min(128, deg - base);
        if (t < c) {
            int eid = csr[b0 + base + t];
            wgt[t] = __expf(score[eid] - m) * inv;
            sidx[t] = src[eid];
        }
        __syncthreads();
        for (int i = 0; i < c; i++) acc += wgt[i] * b2f(hs[(size_t)sidx[i] * DIM + t]);
        __syncthreads();
    }
    h[(size_t)n * DIM + t] = f2b(fmaxf(acc, 0.f));
}

// ---------------- sort each node's 128 features ascending ----------------
__global__ __launch_bounds__(128) void sort_rows(const float* __restrict__ h2,
                                                 float* __restrict__ hsort,
                                                 float* __restrict__ maxval) {
    __shared__ float buf[128];
    int n = blockIdx.x, t = threadIdx.x;
    buf[t] = h2[(size_t)n * DIM + t];
    __syncthreads();
    for (int k = 2; k <= 128; k <<= 1) {
        for (int j = k >> 1; j > 0; j >>= 1) {
            int ixj = t ^ j;
            float a = buf[t], b = buf[ixj];
            __syncthreads();
            bool up = ((t & k) == 0);
            float mn = fminf(a, b), mx = fmaxf(a, b);
            buf[t] = up ? ((t < ixj) ? mn : mx) : ((t < ixj) ? mx : mn);
            __syncthreads();
        }
    }
    hsort[(size_t)n * DIM + t] = buf[t];
    if (t == 127) maxval[n] = buf[127];
}

// ---------------- per-graph top-k + gather pooled rows ----------------
__global__ __launch_bounds__(256) void topk_pool(const float* __restrict__ maxval,
                                                 const float* __restrict__ hsort,
                                                 float* __restrict__ pooled) {
    __shared__ float v[256];
    __shared__ int id[256];
    int b = blockIdx.x, t = threadIdx.x;
    v[t] = (t < NPG) ? maxval[b * NPG + t] : -1e30f;
    id[t] = t;
    __syncthreads();
    for (int k = 2; k <= 256; k <<= 1) {
        for (int j = k >> 1; j > 0; j >>= 1) {
            int ixj = t ^ j;
            float va = v[t], vb = v[ixj];
            int ia = id[t], ib = id[ixj];
            __syncthreads();
            bool dirDesc = ((t & k) == 0);
            bool cmp = (va > vb) || (va == vb && ia < ib);
            bool takeMine = ((t < ixj) == (dirDesc == cmp));
            v[t] = takeMine ? va : vb;
            id[t] = takeMine ? ia : ib;
            __syncthreads();
        }
    }
    for (int i = t; i < KPOOL * DIM; i += 256) {
        int kk = i >> 7, d = i & 127;
        pooled[((size_t)b * KPOOL + kk) * DIM + d] = hsort[((size_t)b * NPG + id[kk]) * DIM + d];
    }
}

// ---------------- ft split-K ----------------
__global__ __launch_bounds__(256) void ft_partial(
    const float* __restrict__ pooled, const float* __restrict__ W3,
    float* __restrict__ part) {
    __shared__ float ps[512];
    __shared__ float red[256];
    int b = blockIdx.x, s = blockIdx.y;
    int t = threadIdx.x;
    int d = t & 127, half = t >> 7;
    for (int i = t; i < 512; i += 256) ps[i] = pooled[(size_t)b * 4096 + s * 512 + i];
    __syncthreads();
    float acc = 0.f;
    const float* Wp = W3 + (size_t)(s * 512 + half * 256) * DIM + d;
    const float* pp = ps + half * 256;
#pragma unroll 4
    for (int kk = 0; kk < 256; kk++) acc += pp[kk] * Wp[(size_t)kk * DIM];
    red[t] = acc;
    __syncthreads();
    if (t < 128) part[((size_t)b * 8 + s) * DIM + t] = red[t] + red[t + 128];
}

__global__ __launch_bounds__(128) void ft_reduce(
    const float* __restrict__ part, const float* __restrict__ al3,
    const float* __restrict__ ar3, float* __restrict__ ft,
    float* __restrict__ sl, float* __restrict__ sr) {
    __shared__ float r1[128], r2[128];
    int b = blockIdx.x, d = threadIdx.x;
    float acc = 0.f;
#pragma unroll
    for (int s = 0; s < 8; s++) acc += part[((size_t)b * 8 + s) * DIM + d];
    ft[b * DIM + d] = acc;
    r1[d] = acc * al3[d];
    r2[d] = acc * ar3[d];
    __syncthreads();
    for (int s = 64; s > 0; s >>= 1) {
        if (d < s) { r1[d] += r1[d + s]; r2[d] += r2[d + s]; }
        __syncthreads();
    }
    if (d == 0) { sl[b] = r1[0]; sr[b] = r2[0]; }
}

// ---------------- final-graph GAT ----------------
__global__ __launch_bounds__(128) void fg_kernel(
    const int* __restrict__ fg_src, const int* __restrict__ fg_dst,
    const float* __restrict__ sl, const float* __restrict__ sr,
    const float* __restrict__ ft, const float* __restrict__ b3,
    float* __restrict__ g) {
    __shared__ int list[EFE];
    __shared__ float wgt[EFE];
    __shared__ float red[128];
    __shared__ int cnt;
    int b = blockIdx.x, t = threadIdx.x;
    if (t == 0) cnt = 0;
    __syncthreads();
    for (int e = t; e < EFE; e += 128)
        if (fg_dst[e] == b) { int p = atomicAdd(&cnt, 1); list[p] = e; }
    __syncthreads();
    int deg = cnt;
    float srb = sr[b];
    float m = -1e30f;
    for (int j = t; j < deg; j += 128) {
        float s = sl[fg_src[list[j]]] + srb;
        s = s > 0.f ? s : 0.2f * s;
        m = fmaxf(m, s);
    }
    red[t] = m;
    __syncthreads();
    for (int s = 64; s > 0; s >>= 1) { if (t < s) red[t] = fmaxf(red[t], red[t + s]); __syncthreads(); }
    m = red[0];
    __syncthreads();
    float se = 0.f;
    for (int j = t; j < deg; j += 128) {
        float s = sl[fg_src[list[j]]] + srb;
        s = s > 0.f ? s : 0.2f * s;
        se += __expf(s - m);
    }
    red[t] = se;
    __syncthreads();
    for (int s = 64; s > 0; s >>= 1) { if (t < s) red[t] += red[t + s]; __syncthreads(); }
    float inv = (deg > 0) ? 1.f / red[0] : 0.f;
    __syncthreads();
    for (int j = t; j < deg; j += 128) {
        float s = sl[fg_src[list[j]]] + srb;
        s = s > 0.f ? s : 0.2f * s;
        wgt[j] = __expf(s - m) * inv;
    }
    __syncthreads();
    float acc = 0.f;
    for (int j = 0; j < deg; j++) acc += wgt[j] * ft[(size_t)fg_src[list[j]] * DIM + t];
    g[b * DIM + t] = fmaxf(acc + b3[t], 0.f);
}

// ---------------- g2 = relu(g @ Wl + bl) ----------------
__global__ __launch_bounds__(128) void gl_kernel(const float* __restrict__ g,
                                                 const float* __restrict__ Wl,
                                                 const float* __restrict__ bl,
                                                 float* __restrict__ g2) {
    __shared__ float gs[128];
    int b = blockIdx.x, d = threadIdx.x;
    gs[d] = g[b * DIM + d];
    __syncthreads();
    float acc = 0.f;
    for (int k = 0; k < 128; k++) acc += gs[k] * Wl[k * DIM + d];
    g2[b * DIM + d] = fmaxf(acc + bl[d], 0.f);
}

// ---------------- out = g2 @ Wc + bc ----------------
__global__ __launch_bounds__(256) void out_kernel(const float* __restrict__ g2,
                                                  const float* __restrict__ Wc,
                                                  const float* __restrict__ bc,
                                                  float* __restrict__ out) {
    int i = threadIdx.x;
    int b = i >> 1, j = i & 1;
    float acc = bc[j];
    for (int k = 0; k < 128; k++) acc += g2[b * DIM + k] * Wc[k * 2 + j];
    out[b * 2 + j] = acc;
}

extern "C" void kernel_launch(void* const* d_in, const int* in_sizes, int n_in,
                              void* d_out, int out_size, void* d_ws, size_t ws_size,
                              hipStream_t stream) {
    const int* tokens_h = (const int*)d_in[0];
    const int* tokens_e = (const int*)d_in[1];
    const int* src = (const int*)d_in[2];
    const int* dst = (const int*)d_in[3];
    const int* fg_src = (const int*)d_in[4];
    const int* fg_dst = (const int*)d_in[5];
    const float* token_emb = (const float*)d_in[6];
    const float* e_token_emb = (const float*)d_in[7];
    const float* W_ni = (const float*)d_in[8];
    const float* W_nj = (const float*)d_in[9];
    const float* W_fij = (const float*)d_in[10];
    const float* W_node = (const float*)d_in[11];
    const float* attn_e = (const float*)d_in[12];
    const float* bias_e = (const float*)d_in[13];
    const float* Wf = (const float*)d_in[14];
    const float* bf_ = (const float*)d_in[15];
    const float* W3 = (const float*)d_in[16];
    const float* al3 = (const float*)d_in[17];
    const float* ar3 = (const float*)d_in[18];
    const float* b3 = (const float*)d_in[19];
    const float* Wl = (const float*)d_in[20];
    const float* bl = (const float*)d_in[21];
    const float* Wc = (const float*)d_in[22];
    const float* bc = (const float*)d_in[23];
    float* out = (float*)d_out;

    char* w = (char*)d_ws;
    auto alloc = [&](size_t b) -> char* {
        char* p = w;
        w += (b + 255) & ~(size_t)255;
        return p;
    };
    ushort_t* h = (ushort_t*)alloc((size_t)N_NODES * DIM * 2);
    ushort_t* fni = (ushort_t*)alloc((size_t)N_NODES * DIM * 2);
    ushort_t* fnj = (ushort_t*)alloc((size_t)N_NODES * DIM * 2);
    ushort_t* hs = (ushort_t*)alloc((size_t)N_NODES * DIM * 2);
    ushort_t* e = (ushort_t*)alloc((size_t)N_EDGES * DIM * 2);
    float* score = (float*)alloc((size_t)N_EDGES * 4);
    int* deg = (int*)alloc((size_t)N_NODES * 4);
    int* off = (int*)alloc((size_t)(N_NODES + 1) * 4);
    int* cursor = (int*)alloc((size_t)N_NODES * 4);
    int* csr = (int*)alloc((size_t)N_EDGES * 4);
    float* eftab = (float*)alloc(100 * DIM * 4);
    float* maxval = (float*)alloc((size_t)N_NODES * 4);
    float* pooled = (float*)alloc((size_t)BGR * KPOOL * DIM * 4);
    float* ft = (float*)alloc(BGR * DIM * 4);
    float* part = (float*)alloc((size_t)BGR * 8 * DIM * 4);
    float* sl = (float*)alloc(BGR * 4);
    float* sr = (float*)alloc(BGR * 4);
    float* g = (float*)alloc(BGR * DIM * 4);
    float* g2 = (float*)alloc(BGR * DIM * 4);
    ushort_t* Wf7 = (ushort_t*)alloc((size_t)NLAYERS * DIM * DIM * 2);
    ushort_t* Wn = (ushort_t*)alloc((size_t)3 * NLAYERS * DIM * DIM * 2);
    float* h2 = (float*)e;
    float* hsort = (float*)((char*)e + (size_t)16 * 1024 * 1024);

    // weight prep
    wfprep<<<(NLAYERS * DIM * DIM) / 256, 256, 0, stream>>>(W_fij, Wf7);
    wnprep<<<(3 * NLAYERS * DIM * DIM) / 256, 256, 0, stream>>>(W_ni, W_nj, W_node, Wn);

    // CSR build
    zero_deg<<<(N_NODES + 255) / 256, 256, 0, stream>>>(deg, N_NODES);
    count_deg<<<N_EDGES / 256, 256, 0, stream>>>(dst, deg, N_EDGES);
    scan_kernel<<<1, 1024, 0, stream>>>(deg, off, cursor, N_NODES);
    scatter_csr<<<N_EDGES / 256, 256, 0, stream>>>(dst, cursor, csr, N_EDGES);

    init_h<<<(N_NODES * DIM) / 256, 256, 0, stream>>>(tokens_h, token_emb, h);
    eftab_kernel<<<100, 128, 0, stream>>>(e_token_emb, W_fij, eftab);

    for (int l = 0; l < NLAYERS; l++) {
        node_gemm_mfma<<<dim3(N_NODES / 64, 3), 256, 0, stream>>>(
            h, Wn + l * 16384, fni, fnj, hs);
        if (l == 0) {
            edge0<<<(N_EDGES * 32) / 256, 256, 0, stream>>>(
                tokens_e, eftab, fni, fnj, src, dst, attn_e, bias_e, e, score);
        } else {
            edge_gemm_mfma<<<N_EDGES / 64, 256, 0, stream>>>(
                e, fni, fnj, src, dst, Wf7 + l * DIM * DIM,
                attn_e + l * DIM, bias_e + l * DIM, score);
        }
        agg_kernel<<<N_NODES, 128, 0, stream>>>(off, csr, src, score, hs, h);
    }

    node_gemm1<<<N_NODES / 64, 256, 0, stream>>>(h, Wf, bf_, h2);
    sort_rows<<<N_NODES, 128, 0, stream>>>(h2, hsort, maxval);
    topk_pool<<<BGR, 256, 0, stream>>>(maxval, hsort, pooled);
    ft_partial<<<dim3(BGR, 8), 256, 0, stream>>>(pooled, W3, part);
    ft_reduce<<<BGR, 128, 0, stream>>>(part, al3, ar3, ft, sl, sr);
    fg_kernel<<<BGR, 128, 0, stream>>>(fg_src, fg_dst, sl, sr, ft, b3, g);
    gl_kernel<<<BGR, 128, 0, stream>>>(g, Wl, bl, g2);
    out_kernel<<<1, 256, 0, stream>>>(g2, Wc, bc, out);
}

// Round 9
// 1421.050 us; speedup vs baseline: 1.7662x; 1.0499x over previous
//
#include <hip/hip_runtime.h>

#define N_NODES 25600
#define N_EDGES 409600
#define BGR 128
#define EFE 1024
#define DIM 128
#define NLAYERS 8
#define KPOOL 32
#define NPG 200

typedef unsigned short ushort_t;
typedef __attribute__((ext_vector_type(8))) short bf16x8;
typedef __attribute__((ext_vector_type(4))) float f32x4;

#define STG_S 144  // per-wave C-staging stride (bf16 elems)

__device__ __forceinline__ float b2f(ushort_t v) {
    return __uint_as_float(((unsigned int)v) << 16);
}
__device__ __forceinline__ ushort_t f2b(float f) {
    unsigned int u = __float_as_uint(f);
    unsigned int r = (u + 0x7fffu + ((u >> 16) & 1u)) >> 16;
    return (ushort_t)r;
}
__device__ __forceinline__ uint2 pack4(float4 v) {
    uint2 p;
    p.x = (unsigned int)f2b(v.x) | ((unsigned int)f2b(v.y) << 16);
    p.y = (unsigned int)f2b(v.z) | ((unsigned int)f2b(v.w) << 16);
    return p;
}

// ---------------- W_fij -> fragment-linear bf16 (proven R6) ----------------
__global__ void wfprep(const float* __restrict__ W, ushort_t* __restrict__ Wf) {
    int idx = blockIdx.x * 256 + threadIdx.x;  // 8 * 16384
    int l = idx >> 14, rem = idx & 16383;
    int j = rem & 7, lane = (rem >> 3) & 63, nt = (rem >> 9) & 7, kc = rem >> 12;
    int q = lane >> 4, r = lane & 15;
    int k = kc * 32 + q * 8 + j, n = nt * 16 + r;
    Wf[idx] = f2b(W[l * 16384 + k * 128 + n]);
}

// W_ni / W_nj / W_node -> fragment-linear bf16, layout [m][l][16384]
__global__ void wnprep(const float* __restrict__ Wni, const float* __restrict__ Wnj,
                       const float* __restrict__ Wnode, ushort_t* __restrict__ Wn) {
    int idx = blockIdx.x * 256 + threadIdx.x;  // 3 * 8 * 16384
    int m = idx >> 17;
    int l = (idx >> 14) & 7;
    int rem = idx & 16383;
    int j = rem & 7, lane = (rem >> 3) & 63, nt = (rem >> 9) & 7, kc = rem >> 12;
    int q = lane >> 4, r = lane & 15;
    int k = kc * 32 + q * 8 + j, n = nt * 16 + r;
    const float* W = (m == 0) ? Wni : (m == 1) ? Wnj : Wnode;
    Wn[idx] = f2b(W[l * 16384 + k * 128 + n]);
}

// ---------------- zero deg ----------------
__global__ void zero_deg(int* __restrict__ deg, int n) {
    int i = blockIdx.x * 256 + threadIdx.x;
    if (i < n) deg[i] = 0;
}

// ---------------- CSR build ----------------
__global__ void count_deg(const int* __restrict__ dst, int* __restrict__ deg, int n) {
    int i = blockIdx.x * 256 + threadIdx.x;
    if (i < n) atomicAdd(&deg[dst[i]], 1);
}

__global__ __launch_bounds__(1024) void scan_kernel(const int* __restrict__ deg,
                                                    int* __restrict__ off,
                                                    int* __restrict__ cursor, int n) {
    __shared__ int buf[1024];
    __shared__ int carry;
    int t = threadIdx.x;
    if (t == 0) carry = 0;
    __syncthreads();
    for (int base = 0; base < n; base += 1024) {
        int v = (base + t < n) ? deg[base + t] : 0;
        buf[t] = v;
        __syncthreads();
        for (int s = 1; s < 1024; s <<= 1) {
            int x = (t >= s) ? buf[t - s] : 0;
            __syncthreads();
            buf[t] += x;
            __syncthreads();
        }
        int excl = buf[t] - v;
        if (base + t < n) { off[base + t] = carry + excl; cursor[base + t] = carry + excl; }
        __syncthreads();
        if (t == 1023) carry += buf[1023];
        __syncthreads();
    }
    if (t == 0) off[n] = carry;
}

// scatter edges into CSR (dst-sorted) order; build permuted src/dst/token arrays
__global__ void scatter_perm(const int* __restrict__ src, const int* __restrict__ dst,
                             const int* __restrict__ tokens_e, int* __restrict__ cursor,
                             int* __restrict__ psrc, int* __restrict__ pdst,
                             int* __restrict__ ptok, int n) {
    int i = blockIdx.x * 256 + threadIdx.x;
    if (i < n) {
        int p = atomicAdd(&cursor[dst[i]], 1);
        psrc[p] = src[i];
        pdst[p] = dst[i];
        ptok[p] = tokens_e[i];
    }
}

// ---------------- init (h bf16) ----------------
__global__ void init_h(const int* __restrict__ tok, const float* __restrict__ emb,
                       ushort_t* __restrict__ h) {
    int i = blockIdx.x * 256 + threadIdx.x;
    int r = i >> 7, d = i & 127;
    float v = emb[tok[r] * DIM + d];
    h[i] = f2b(fmaxf(v, 0.f));
}

// eftab[t][d] = sum_k e_token_emb[t][k] * W_fij0[k][d]
__global__ __launch_bounds__(128) void eftab_kernel(const float* __restrict__ etab,
                                                    const float* __restrict__ W,
                                                    float* __restrict__ out) {
    int r = blockIdx.x, d = threadIdx.x;
    float acc = 0.f;
    for (int k = 0; k < DIM; k++)
        acc += etab[r * DIM + k] * W[k * DIM + d];
    out[r * DIM + d] = acc;
}

// ---------------- MFMA node GEMM: grid (400, 3) ----------------
__global__ __launch_bounds__(256, 4) void node_gemm_mfma(
    const ushort_t* __restrict__ h,
    const ushort_t* __restrict__ Wn,
    ushort_t* __restrict__ C0, ushort_t* __restrict__ C1, ushort_t* __restrict__ C2) {
    __shared__ __align__(16) ushort_t wF[16384];
    int tid = threadIdx.x, wv = tid >> 6, lane = tid & 63;
    int r = lane & 15, q = lane >> 4;
    int el = lane >> 2, qq = lane & 3;
    int m = blockIdx.y;
    size_t row = (size_t)blockIdx.x * 64 + 16 * wv;

    {
        const uint4* wg = (const uint4*)(Wn + (size_t)m * NLAYERS * 16384);
        uint4* ws = (uint4*)wF;
        for (int i = tid; i < 2048; i += 256) ws[i] = wg[i];
    }
    __syncthreads();

    const ushort_t* aRow = h + (row + r) * DIM + q * 8;
    bf16x8 a0 = *(const bf16x8*)(aRow);
    bf16x8 a1 = *(const bf16x8*)(aRow + 32);
    bf16x8 a2 = *(const bf16x8*)(aRow + 64);
    bf16x8 a3 = *(const bf16x8*)(aRow + 96);

    f32x4 acc[8] = {};
    const bf16x8* wfrag = (const bf16x8*)wF;
#pragma unroll
    for (int nt = 0; nt < 8; nt++)
        acc[nt] = __builtin_amdgcn_mfma_f32_16x16x32_bf16(a0, wfrag[(0 * 8 + nt) * 64 + lane], acc[nt], 0, 0, 0);
#pragma unroll
    for (int nt = 0; nt < 8; nt++)
        acc[nt] = __builtin_amdgcn_mfma_f32_16x16x32_bf16(a1, wfrag[(1 * 8 + nt) * 64 + lane], acc[nt], 0, 0, 0);
#pragma unroll
    for (int nt = 0; nt < 8; nt++)
        acc[nt] = __builtin_amdgcn_mfma_f32_16x16x32_bf16(a2, wfrag[(2 * 8 + nt) * 64 + lane], acc[nt], 0, 0, 0);
#pragma unroll
    for (int nt = 0; nt < 8; nt++)
        acc[nt] = __builtin_amdgcn_mfma_f32_16x16x32_bf16(a3, wfrag[(3 * 8 + nt) * 64 + lane], acc[nt], 0, 0, 0);
    __syncthreads();

    ushort_t* ss = wF + wv * 16 * STG_S;
#pragma unroll
    for (int nt = 0; nt < 8; nt++)
#pragma unroll
        for (int rg = 0; rg < 4; rg++)
            ss[(q * 4 + rg) * STG_S + nt * 16 + r] = f2b(acc[nt][rg]);

    ushort_t* Cp = (m == 0) ? C0 : (m == 1) ? C1 : C2;
    const uint4* sp = (const uint4*)(ss + el * STG_S + qq * 32);
    uint4* cp = (uint4*)(Cp + (row + el) * DIM + qq * 32);
#pragma unroll
    for (int cc = 0; cc < 4; cc++) cp[cc] = sp[cc];
}

// single-W with bias + relu (final Wf): h bf16 in, fp32 out
__global__ __launch_bounds__(256) void node_gemm1(
    const ushort_t* __restrict__ A, const float* __restrict__ W,
    const float* __restrict__ bias, float* __restrict__ C) {
    __shared__ float As[64 * 128];
    __shared__ uint2 Ws4[128 * 32];
    int tid = threadIdx.x;
    size_t row0 = (size_t)blockIdx.x * 64;
    const uint2* Ag = (const uint2*)(A + row0 * DIM);
    for (int f = tid; f < 64 * 32; f += 256) {
        uint2 v = Ag[f];
        ((float4*)As)[f] = make_float4(
            __uint_as_float(v.x << 16), __uint_as_float(v.x & 0xffff0000u),
            __uint_as_float(v.y << 16), __uint_as_float(v.y & 0xffff0000u));
    }
    const float4* Wg = (const float4*)W;
    for (int i = tid; i < 128 * 32; i += 256) Ws4[i] = pack4(Wg[i]);
    __syncthreads();
    int cq = tid & 31, r0 = (tid >> 5) * 8, c0 = cq * 4;
    float acc[8][4] = {};
    for (int k = 0; k < 128; k++) {
        uint2 wp = Ws4[k * 32 + cq];
        float w0 = __uint_as_float(wp.x << 16);
        float w1 = __uint_as_float(wp.x & 0xffff0000u);
        float w2 = __uint_as_float(wp.y << 16);
        float w3 = __uint_as_float(wp.y & 0xffff0000u);
#pragma unroll
        for (int i = 0; i < 8; i++) {
            float a = As[(r0 + i) * 128 + k];
            acc[i][0] += a * w0; acc[i][1] += a * w1;
            acc[i][2] += a * w2; acc[i][3] += a * w3;
        }
    }
    float b0 = bias[c0], b1 = bias[c0 + 1], b2v = bias[c0 + 2], b3v = bias[c0 + 3];
#pragma unroll
    for (int i = 0; i < 8; i++) {
        *(float4*)&C[(row0 + r0 + i) * DIM + c0] =
            make_float4(fmaxf(acc[i][0] + b0, 0.f), fmaxf(acc[i][1] + b1, 0.f),
                        fmaxf(acc[i][2] + b2v, 0.f), fmaxf(acc[i][3] + b3v, 0.f));
    }
}

// ---------------- MFMA edge GEMM (edges in CSR-permuted order) ----------------
__global__ __launch_bounds__(256, 4) void edge_gemm_mfma(
    ushort_t* __restrict__ e,
    const ushort_t* __restrict__ fni, const ushort_t* __restrict__ fnj,
    const int* __restrict__ psrc, const int* __restrict__ pdst,
    const ushort_t* __restrict__ Wf,
    const float* __restrict__ attn, const float* __restrict__ bias,
    float* __restrict__ score) {
    __shared__ __align__(16) ushort_t wF[16384];

    int tid = threadIdx.x;
    {
        const uint4* wg = (const uint4*)Wf;
        uint4* ws = (uint4*)wF;
        for (int i = tid; i < 2048; i += 256) ws[i] = wg[i];
    }
    __syncthreads();

    int wv = tid >> 6, lane = tid & 63;
    int r = lane & 15, q = lane >> 4;
    int el = lane >> 2, qq = lane & 3;
    size_t row = (size_t)blockIdx.x * 64 + 16 * wv;

    const ushort_t* aRow = e + (row + r) * DIM + q * 8;
    bf16x8 a0 = *(const bf16x8*)(aRow);
    bf16x8 a1 = *(const bf16x8*)(aRow + 32);
    bf16x8 a2 = *(const bf16x8*)(aRow + 64);
    bf16x8 a3 = *(const bf16x8*)(aRow + 96);

    f32x4 acc[8] = {};
    const bf16x8* wfrag = (const bf16x8*)wF;
#pragma unroll
    for (int nt = 0; nt < 8; nt++)
        acc[nt] = __builtin_amdgcn_mfma_f32_16x16x32_bf16(a0, wfrag[(0 * 8 + nt) * 64 + lane], acc[nt], 0, 0, 0);
#pragma unroll
    for (int nt = 0; nt < 8; nt++)
        acc[nt] = __builtin_amdgcn_mfma_f32_16x16x32_bf16(a1, wfrag[(1 * 8 + nt) * 64 + lane], acc[nt], 0, 0, 0);
#pragma unroll
    for (int nt = 0; nt < 8; nt++)
        acc[nt] = __builtin_amdgcn_mfma_f32_16x16x32_bf16(a2, wfrag[(2 * 8 + nt) * 64 + lane], acc[nt], 0, 0, 0);
#pragma unroll
    for (int nt = 0; nt < 8; nt++)
        acc[nt] = __builtin_amdgcn_mfma_f32_16x16x32_bf16(a3, wfrag[(3 * 8 + nt) * 64 + lane], acc[nt], 0, 0, 0);
    __syncthreads();

    ushort_t* ss = wF + wv * 16 * STG_S;
#pragma unroll
    for (int nt = 0; nt < 8; nt++)
#pragma unroll
        for (int rg = 0; rg < 4; rg++)
            ss[(q * 4 + rg) * STG_S + nt * 16 + r] = f2b(acc[nt][rg]);

    size_t eid = row + el;
    int sv = psrc[eid], dv = pdst[eid];
    const uint4* nip = (const uint4*)(fni + (size_t)sv * DIM + qq * 32);
    const uint4* njp = (const uint4*)(fnj + (size_t)dv * DIM + qq * 32);
    const uint4* sp = (const uint4*)(ss + el * STG_S + qq * 32);
    uint4 outv[4];
    float p = 0.f;
#pragma unroll
    for (int cc = 0; cc < 4; cc++) {
        uint4 avq = sp[cc];
        uint4 niq = nip[cc];
        uint4 njq = njp[cc];
#pragma unroll
        for (int u = 0; u < 4; u++) {
            unsigned int aw = ((const unsigned int*)&avq)[u];
            unsigned int nw = ((const unsigned int*)&niq)[u];
            unsigned int jw = ((const unsigned int*)&njq)[u];
            int c = qq * 32 + cc * 8 + u * 2;
            float v0 = __uint_as_float(aw << 16) + __uint_as_float(nw << 16) +
                       __uint_as_float(jw << 16) + bias[c];
            float v1 = __uint_as_float(aw & 0xffff0000u) + __uint_as_float(nw & 0xffff0000u) +
                       __uint_as_float(jw & 0xffff0000u) + bias[c + 1];
            v0 = v0 > 0.f ? v0 : 0.01f * v0;
            v1 = v1 > 0.f ? v1 : 0.01f * v1;
            ((unsigned int*)&outv[cc])[u] =
                (unsigned int)f2b(v0) | ((unsigned int)f2b(v1) << 16);
            p += v0 * attn[c] + v1 * attn[c + 1];
        }
    }
    uint4* ep = (uint4*)(e + eid * DIM + qq * 32);
#pragma unroll
    for (int cc = 0; cc < 4; cc++) ep[cc] = outv[cc];
    p += __shfl_xor(p, 1);
    p += __shfl_xor(p, 2);
    if (qq == 0) score[eid] = p;
}

// ---------------- layer-0 edge kernel (permuted order) ----------------
__global__ __launch_bounds__(256) void edge0(
    const int* __restrict__ ptok, const float* __restrict__ eftab,
    const ushort_t* __restrict__ fni, const ushort_t* __restrict__ fnj,
    const int* __restrict__ psrc, const int* __restrict__ pdst,
    const float* __restrict__ attn, const float* __restrict__ bias,
    ushort_t* __restrict__ e, float* __restrict__ score) {
    unsigned int gid = blockIdx.x * 256 + threadIdx.x;
    unsigned int eid = gid >> 5;
    int cq = gid & 31, c0 = cq * 4;
    int tok = ptok[eid];
    int sv = psrc[eid], dv = pdst[eid];
    float4 t = *(const float4*)&eftab[tok * DIM + c0];
    uint2 niw = *(const uint2*)(fni + (size_t)sv * DIM + c0);
    uint2 njw = *(const uint2*)(fnj + (size_t)dv * DIM + c0);
    float ni0 = __uint_as_float(niw.x << 16), ni1 = __uint_as_float(niw.x & 0xffff0000u);
    float ni2 = __uint_as_float(niw.y << 16), ni3 = __uint_as_float(niw.y & 0xffff0000u);
    float nj0 = __uint_as_float(njw.x << 16), nj1 = __uint_as_float(njw.x & 0xffff0000u);
    float nj2 = __uint_as_float(njw.y << 16), nj3 = __uint_as_float(njw.y & 0xffff0000u);
    float v0 = t.x + ni0 + nj0 + bias[c0];
    float v1 = t.y + ni1 + nj1 + bias[c0 + 1];
    float v2 = t.z + ni2 + nj2 + bias[c0 + 2];
    float v3 = t.w + ni3 + nj3 + bias[c0 + 3];
    v0 = v0 > 0.f ? v0 : 0.01f * v0;
    v1 = v1 > 0.f ? v1 : 0.01f * v1;
    v2 = v2 > 0.f ? v2 : 0.01f * v2;
    v3 = v3 > 0.f ? v3 : 0.01f * v3;
    *(uint2*)(e + (size_t)eid * DIM + c0) = pack4(make_float4(v0, v1, v2, v3));
    float p = v0 * attn[c0] + v1 * attn[c0 + 1] + v2 * attn[c0 + 2] + v3 * attn[c0 + 3];
#pragma unroll
    for (int o = 1; o < 32; o <<= 1) p += __shfl_xor(p, o);
    if (cq == 0) score[eid] = p;
}

// ---------------- wave-per-node softmax + aggregation: NO barriers ----------------
// score/psrc are contiguous per node segment (CSR-permuted). 64 lanes x 2 channels.
__global__ __launch_bounds__(256) void agg_wave(
    const int* __restrict__ off, const int* __restrict__ psrc,
    const float* __restrict__ score, const ushort_t* __restrict__ hs,
    ushort_t* __restrict__ h) {
    int node = blockIdx.x * 4 + (threadIdx.x >> 6);
    int lane = threadIdx.x & 63;
    int b0 = off[node];
    int deg = off[node + 1] - b0;

    float m = -1e30f;
    for (int j = lane; j < deg; j += 64) m = fmaxf(m, score[b0 + j]);
#pragma unroll
    for (int o = 32; o > 0; o >>= 1) m = fmaxf(m, __shfl_xor(m, o));
    float se = 0.f;
    for (int j = lane; j < deg; j += 64) se += __expf(score[b0 + j] - m);
#pragma unroll
    for (int o = 32; o > 0; o >>= 1) se += __shfl_xor(se, o);
    float inv = (deg > 0) ? 1.f / se : 0.f;

    float acc0 = 0.f, acc1 = 0.f;
    for (int base = 0; base < deg; base += 64) {
        int cnt = min(64, deg - base);
        float wgt = 0.f;
        int sidx = 0;
        if (lane < cnt) {
            wgt = __expf(score[b0 + base + lane] - m) * inv;
            sidx = psrc[b0 + base + lane];
        }
        for (int i = 0; i < cnt; i++) {
            float wi = __shfl(wgt, i);
            int si = __shfl(sidx, i);
            unsigned int hv = *(const unsigned int*)(hs + (size_t)si * DIM + lane * 2);
            acc0 += wi * __uint_as_float(hv << 16);
            acc1 += wi * __uint_as_float(hv & 0xffff0000u);
        }
    }
    unsigned int outp = (unsigned int)f2b(fmaxf(acc0, 0.f)) |
                        ((unsigned int)f2b(fmaxf(acc1, 0.f)) << 16);
    *(unsigned int*)(h + (size_t)node * DIM + lane * 2) = outp;
}

// ---------------- sort each node's 128 features ascending ----------------
__global__ __launch_bounds__(128) void sort_rows(const float* __restrict__ h2,
                                                 float* __restrict__ hsort,
                                                 float* __restrict__ maxval) {
    __shared__ float buf[128];
    int n = blockIdx.x, t = threadIdx.x;
    buf[t] = h2[(size_t)n * DIM + t];
    __syncthreads();
    for (int k = 2; k <= 128; k <<= 1) {
        for (int j = k >> 1; j > 0; j >>= 1) {
            int ixj = t ^ j;
            float a = buf[t], b = buf[ixj];
            __syncthreads();
            bool up = ((t & k) == 0);
            float mn = fminf(a, b), mx = fmaxf(a, b);
            buf[t] = up ? ((t < ixj) ? mn : mx) : ((t < ixj) ? mx : mn);
            __syncthreads();
        }
    }
    hsort[(size_t)n * DIM + t] = buf[t];
    if (t == 127) maxval[n] = buf[127];
}

// ---------------- per-graph top-k + gather pooled rows ----------------
__global__ __launch_bounds__(256) void topk_pool(const float* __restrict__ maxval,
                                                 const float* __restrict__ hsort,
                                                 float* __restrict__ pooled) {
    __shared__ float v[256];
    __shared__ int id[256];
    int b = blockIdx.x, t = threadIdx.x;
    v[t] = (t < NPG) ? maxval[b * NPG + t] : -1e30f;
    id[t] = t;
    __syncthreads();
    for (int k = 2; k <= 256; k <<= 1) {
        for (int j = k >> 1; j > 0; j >>= 1) {
            int ixj = t ^ j;
            float va = v[t], vb = v[ixj];
            int ia = id[t], ib = id[ixj];
            __syncthreads();
            bool dirDesc = ((t & k) == 0);
            bool cmp = (va > vb) || (va == vb && ia < ib);
            bool takeMine = ((t < ixj) == (dirDesc == cmp));
            v[t] = takeMine ? va : vb;
            id[t] = takeMine ? ia : ib;
            __syncthreads();
        }
    }
    for (int i = t; i < KPOOL * DIM; i += 256) {
        int kk = i >> 7, d = i & 127;
        pooled[((size_t)b * KPOOL + kk) * DIM + d] = hsort[((size_t)b * NPG + id[kk]) * DIM + d];
    }
}

// ---------------- ft split-K ----------------
__global__ __launch_bounds__(256) void ft_partial(
    const float* __restrict__ pooled, const float* __restrict__ W3,
    float* __restrict__ part) {
    __shared__ float ps[512];
    __shared__ float red[256];
    int b = blockIdx.x, s = blockIdx.y;
    int t = threadIdx.x;
    int d = t & 127, half = t >> 7;
    for (int i = t; i < 512; i += 256) ps[i] = pooled[(size_t)b * 4096 + s * 512 + i];
    __syncthreads();
    float acc = 0.f;
    const float* Wp = W3 + (size_t)(s * 512 + half * 256) * DIM + d;
    const float* pp = ps + half * 256;
#pragma unroll 4
    for (int kk = 0; kk < 256; kk++) acc += pp[kk] * Wp[(size_t)kk * DIM];
    red[t] = acc;
    __syncthreads();
    if (t < 128) part[((size_t)b * 8 + s) * DIM + t] = red[t] + red[t + 128];
}

__global__ __launch_bounds__(128) void ft_reduce(
    const float* __restrict__ part, const float* __restrict__ al3,
    const float* __restrict__ ar3, float* __restrict__ ft,
    float* __restrict__ sl, float* __restrict__ sr) {
    __shared__ float r1[128], r2[128];
    int b = blockIdx.x, d = threadIdx.x;
    float acc = 0.f;
#pragma unroll
    for (int s = 0; s < 8; s++) acc += part[((size_t)b * 8 + s) * DIM + d];
    ft[b * DIM + d] = acc;
    r1[d] = acc * al3[d];
    r2[d] = acc * ar3[d];
    __syncthreads();
    for (int s = 64; s > 0; s >>= 1) {
        if (d < s) { r1[d] += r1[d + s]; r2[d] += r2[d + s]; }
        __syncthreads();
    }
    if (d == 0) { sl[b] = r1[0]; sr[b] = r2[0]; }
}

// ---------------- final-graph GAT ----------------
__global__ __launch_bounds__(128) void fg_kernel(
    const int* __restrict__ fg_src, const int* __restrict__ fg_dst,
    const float* __restrict__ sl, const float* __restrict__ sr,
    const float* __restrict__ ft, const float* __restrict__ b3,
    float* __restrict__ g) {
    __shared__ int list[EFE];
    __shared__ float wgt[EFE];
    __shared__ float red[128];
    __shared__ int cnt;
    int b = blockIdx.x, t = threadIdx.x;
    if (t == 0) cnt = 0;
    __syncthreads();
    for (int e = t; e < EFE; e += 128)
        if (fg_dst[e] == b) { int p = atomicAdd(&cnt, 1); list[p] = e; }
    __syncthreads();
    int deg = cnt;
    float srb = sr[b];
    float m = -1e30f;
    for (int j = t; j < deg; j += 128) {
        float s = sl[fg_src[list[j]]] + srb;
        s = s > 0.f ? s : 0.2f * s;
        m = fmaxf(m, s);
    }
    red[t] = m;
    __syncthreads();
    for (int s = 64; s > 0; s >>= 1) { if (t < s) red[t] = fmaxf(red[t], red[t + s]); __syncthreads(); }
    m = red[0];
    __syncthreads();
    float se = 0.f;
    for (int j = t; j < deg; j += 128) {
        float s = sl[fg_src[list[j]]] + srb;
        s = s > 0.f ? s : 0.2f * s;
        se += __expf(s - m);
    }
    red[t] = se;
    __syncthreads();
    for (int s = 64; s > 0; s >>= 1) { if (t < s) red[t] += red[t + s]; __syncthreads(); }
    float inv = (deg > 0) ? 1.f / red[0] : 0.f;
    __syncthreads();
    for (int j = t; j < deg; j += 128) {
        float s = sl[fg_src[list[j]]] + srb;
        s = s > 0.f ? s : 0.2f * s;
        wgt[j] = __expf(s - m) * inv;
    }
    __syncthreads();
    float acc = 0.f;
    for (int j = 0; j < deg; j++) acc += wgt[j] * ft[(size_t)fg_src[list[j]] * DIM + t];
    g[b * DIM + t] = fmaxf(acc + b3[t], 0.f);
}

// ---------------- g2 = relu(g @ Wl + bl) ----------------
__global__ __launch_bounds__(128) void gl_kernel(const float* __restrict__ g,
                                                 const float* __restrict__ Wl,
                                                 const float* __restrict__ bl,
                                                 float* __restrict__ g2) {
    __shared__ float gs[128];
    int b = blockIdx.x, d = threadIdx.x;
    gs[d] = g[b * DIM + d];
    __syncthreads();
    float acc = 0.f;
    for (int k = 0; k < 128; k++) acc += gs[k] * Wl[k * DIM + d];
    g2[b * DIM + d] = fmaxf(acc + bl[d], 0.f);
}

// ---------------- out = g2 @ Wc + bc ----------------
__global__ __launch_bounds__(256) void out_kernel(const float* __restrict__ g2,
                                                  const float* __restrict__ Wc,
                                                  const float* __restrict__ bc,
                                                  float* __restrict__ out) {
    int i = threadIdx.x;
    int b = i >> 1, j = i & 1;
    float acc = bc[j];
    for (int k = 0; k < 128; k++) acc += g2[b * DIM + k] * Wc[k * 2 + j];
    out[b * 2 + j] = acc;
}

extern "C" void kernel_launch(void* const* d_in, const int* in_sizes, int n_in,
                              void* d_out, int out_size, void* d_ws, size_t ws_size,
                              hipStream_t stream) {
    const int* tokens_h = (const int*)d_in[0];
    const int* tokens_e = (const int*)d_in[1];
    const int* src = (const int*)d_in[2];
    const int* dst = (const int*)d_in[3];
    const int* fg_src = (const int*)d_in[4];
    const int* fg_dst = (const int*)d_in[5];
    const float* token_emb = (const float*)d_in[6];
    const float* e_token_emb = (const float*)d_in[7];
    const float* W_ni = (const float*)d_in[8];
    const float* W_nj = (const float*)d_in[9];
    const float* W_fij = (const float*)d_in[10];
    const float* W_node = (const float*)d_in[11];
    const float* attn_e = (const float*)d_in[12];
    const float* bias_e = (const float*)d_in[13];
    const float* Wf = (const float*)d_in[14];
    const float* bf_ = (const float*)d_in[15];
    const float* W3 = (const float*)d_in[16];
    const float* al3 = (const float*)d_in[17];
    const float* ar3 = (const float*)d_in[18];
    const float* b3 = (const float*)d_in[19];
    const float* Wl = (const float*)d_in[20];
    const float* bl = (const float*)d_in[21];
    const float* Wc = (const float*)d_in[22];
    const float* bc = (const float*)d_in[23];
    float* out = (float*)d_out;

    char* w = (char*)d_ws;
    auto alloc = [&](size_t b) -> char* {
        char* p = w;
        w += (b + 255) & ~(size_t)255;
        return p;
    };
    ushort_t* h = (ushort_t*)alloc((size_t)N_NODES * DIM * 2);
    ushort_t* fni = (ushort_t*)alloc((size_t)N_NODES * DIM * 2);
    ushort_t* fnj = (ushort_t*)alloc((size_t)N_NODES * DIM * 2);
    ushort_t* hs = (ushort_t*)alloc((size_t)N_NODES * DIM * 2);
    ushort_t* e = (ushort_t*)alloc((size_t)N_EDGES * DIM * 2);
    float* score = (float*)alloc((size_t)N_EDGES * 4);
    int* deg = (int*)alloc((size_t)N_NODES * 4);
    int* off = (int*)alloc((size_t)(N_NODES + 1) * 4);
    int* cursor = (int*)alloc((size_t)N_NODES * 4);
    int* psrc = (int*)alloc((size_t)N_EDGES * 4);
    int* pdst = (int*)alloc((size_t)N_EDGES * 4);
    int* ptok = (int*)alloc((size_t)N_EDGES * 4);
    float* eftab = (float*)alloc(100 * DIM * 4);
    float* maxval = (float*)alloc((size_t)N_NODES * 4);
    float* pooled = (float*)alloc((size_t)BGR * KPOOL * DIM * 4);
    float* ft = (float*)alloc(BGR * DIM * 4);
    float* part = (float*)alloc((size_t)BGR * 8 * DIM * 4);
    float* sl = (float*)alloc(BGR * 4);
    float* sr = (float*)alloc(BGR * 4);
    float* g = (float*)alloc(BGR * DIM * 4);
    float* g2 = (float*)alloc(BGR * DIM * 4);
    ushort_t* Wf7 = (ushort_t*)alloc((size_t)NLAYERS * DIM * DIM * 2);
    ushort_t* Wn = (ushort_t*)alloc((size_t)3 * NLAYERS * DIM * DIM * 2);
    float* h2 = (float*)e;
    float* hsort = (float*)((char*)e + (size_t)16 * 1024 * 1024);

    // weight prep
    wfprep<<<(NLAYERS * DIM * DIM) / 256, 256, 0, stream>>>(W_fij, Wf7);
    wnprep<<<(3 * NLAYERS * DIM * DIM) / 256, 256, 0, stream>>>(W_ni, W_nj, W_node, Wn);

    // CSR build + edge permutation (dst-sorted order)
    zero_deg<<<(N_NODES + 255) / 256, 256, 0, stream>>>(deg, N_NODES);
    count_deg<<<N_EDGES / 256, 256, 0, stream>>>(dst, deg, N_EDGES);
    scan_kernel<<<1, 1024, 0, stream>>>(deg, off, cursor, N_NODES);
    scatter_perm<<<N_EDGES / 256, 256, 0, stream>>>(src, dst, tokens_e, cursor,
                                                    psrc, pdst, ptok, N_EDGES);

    init_h<<<(N_NODES * DIM) / 256, 256, 0, stream>>>(tokens_h, token_emb, h);
    eftab_kernel<<<100, 128, 0, stream>>>(e_token_emb, W_fij, eftab);

    for (int l = 0; l < NLAYERS; l++) {
        node_gemm_mfma<<<dim3(N_NODES / 64, 3), 256, 0, stream>>>(
            h, Wn + l * 16384, fni, fnj, hs);
        if (l == 0) {
            edge0<<<(N_EDGES * 32) / 256, 256, 0, stream>>>(
                ptok, eftab, fni, fnj, psrc, pdst, attn_e, bias_e, e, score);
        } else {
            edge_gemm_mfma<<<N_EDGES / 64, 256, 0, stream>>>(
                e, fni, fnj, psrc, pdst, Wf7 + l * DIM * DIM,
                attn_e + l * DIM, bias_e + l * DIM, score);
        }
        agg_wave<<<N_NODES / 4, 256, 0, stream>>>(off, psrc, score, hs, h);
    }

    node_gemm1<<<N_NODES / 64, 256, 0, stream>>>(h, Wf, bf_, h2);
    sort_rows<<<N_NODES, 128, 0, stream>>>(h2, hsort, maxval);
    topk_pool<<<BGR, 256, 0, stream>>>(maxval, hsort, pooled);
    ft_partial<<<dim3(BGR, 8), 256, 0, stream>>>(pooled, W3, part);
    ft_reduce<<<BGR, 128, 0, stream>>>(part, al3, ar3, ft, sl, sr);
    fg_kernel<<<BGR, 128, 0, stream>>>(fg_src, fg_dst, sl, sr, ft, b3, g);
    gl_kernel<<<BGR, 128, 0, stream>>>(g, Wl, bl, g2);
    out_kernel<<<1, 256, 0, stream>>>(g2, Wc, bc, out);
}

// Round 10
// 1374.689 us; speedup vs baseline: 1.8257x; 1.0337x over previous
//
#include <hip/hip_runtime.h>

#define N_NODES 25600
#define N_EDGES 409600
#define BGR 128
#define EFE 1024
#define DIM 128
#define NLAYERS 8
#define KPOOL 32
#define NPG 200

typedef unsigned short ushort_t;
typedef __attribute__((ext_vector_type(8))) short bf16x8;
typedef __attribute__((ext_vector_type(4))) float f32x4;

#define STG_S 144  // per-wave C-staging stride (bf16 elems)

__device__ __forceinline__ float b2f(ushort_t v) {
    return __uint_as_float(((unsigned int)v) << 16);
}
__device__ __forceinline__ ushort_t f2b(float f) {
    unsigned int u = __float_as_uint(f);
    unsigned int r = (u + 0x7fffu + ((u >> 16) & 1u)) >> 16;
    return (ushort_t)r;
}
__device__ __forceinline__ uint2 pack4(float4 v) {
    uint2 p;
    p.x = (unsigned int)f2b(v.x) | ((unsigned int)f2b(v.y) << 16);
    p.y = (unsigned int)f2b(v.z) | ((unsigned int)f2b(v.w) << 16);
    return p;
}

// ---------------- W_fij -> fragment-linear bf16 (proven R6) ----------------
__global__ void wfprep(const float* __restrict__ W, ushort_t* __restrict__ Wf) {
    int idx = blockIdx.x * 256 + threadIdx.x;  // 8 * 16384
    int l = idx >> 14, rem = idx & 16383;
    int j = rem & 7, lane = (rem >> 3) & 63, nt = (rem >> 9) & 7, kc = rem >> 12;
    int q = lane >> 4, r = lane & 15;
    int k = kc * 32 + q * 8 + j, n = nt * 16 + r;
    Wf[idx] = f2b(W[l * 16384 + k * 128 + n]);
}

// W_ni / W_nj / W_node -> fragment-linear bf16, layout [m][l][16384]
__global__ void wnprep(const float* __restrict__ Wni, const float* __restrict__ Wnj,
                       const float* __restrict__ Wnode, ushort_t* __restrict__ Wn) {
    int idx = blockIdx.x * 256 + threadIdx.x;  // 3 * 8 * 16384
    int m = idx >> 17;
    int l = (idx >> 14) & 7;
    int rem = idx & 16383;
    int j = rem & 7, lane = (rem >> 3) & 63, nt = (rem >> 9) & 7, kc = rem >> 12;
    int q = lane >> 4, r = lane & 15;
    int k = kc * 32 + q * 8 + j, n = nt * 16 + r;
    const float* W = (m == 0) ? Wni : (m == 1) ? Wnj : Wnode;
    Wn[idx] = f2b(W[l * 16384 + k * 128 + n]);
}

// ---------------- zero deg ----------------
__global__ void zero_deg(int* __restrict__ deg, int n) {
    int i = blockIdx.x * 256 + threadIdx.x;
    if (i < n) deg[i] = 0;
}

// ---------------- CSR build ----------------
__global__ void count_deg(const int* __restrict__ dst, int* __restrict__ deg, int n) {
    int i = blockIdx.x * 256 + threadIdx.x;
    if (i < n) atomicAdd(&deg[dst[i]], 1);
}

// hierarchical scan: local 1024-scan per block + block sums
__global__ __launch_bounds__(1024) void scan_local(const int* __restrict__ deg,
                                                   int* __restrict__ off,
                                                   int* __restrict__ bsum, int n) {
    __shared__ int buf[1024];
    int b = blockIdx.x, t = threadIdx.x;
    int gi = b * 1024 + t;
    int v = (gi < n) ? deg[gi] : 0;
    buf[t] = v;
    __syncthreads();
    for (int s = 1; s < 1024; s <<= 1) {
        int x = (t >= s) ? buf[t - s] : 0;
        __syncthreads();
        buf[t] += x;
        __syncthreads();
    }
    if (gi < n) off[gi] = buf[t] - v;  // local exclusive
    if (t == 1023) bsum[b] = buf[1023];
}

__global__ void scan_bsum(int* __restrict__ bsum, int nb) {
    if (threadIdx.x == 0) {
        int acc = 0;
        for (int i = 0; i < nb; i++) { int v = bsum[i]; bsum[i] = acc; acc += v; }
    }
}

__global__ void scan_add(int* __restrict__ off, const int* __restrict__ bsum,
                         int* __restrict__ cursor, int n, int total) {
    int i = blockIdx.x * 256 + threadIdx.x;
    if (i < n) {
        int v = off[i] + bsum[i >> 10];
        off[i] = v;
        cursor[i] = v;
    }
    if (i == 0) off[n] = total;
}

// scatter edges into CSR (dst-sorted) order; build permuted src/dst/token arrays
__global__ void scatter_perm(const int* __restrict__ src, const int* __restrict__ dst,
                             const int* __restrict__ tokens_e, int* __restrict__ cursor,
                             int* __restrict__ psrc, int* __restrict__ pdst,
                             int* __restrict__ ptok, int n) {
    int i = blockIdx.x * 256 + threadIdx.x;
    if (i < n) {
        int p = atomicAdd(&cursor[dst[i]], 1);
        psrc[p] = src[i];
        pdst[p] = dst[i];
        ptok[p] = tokens_e[i];
    }
}

// ---------------- init (h bf16) ----------------
__global__ void init_h(const int* __restrict__ tok, const float* __restrict__ emb,
                       ushort_t* __restrict__ h) {
    int i = blockIdx.x * 256 + threadIdx.x;
    int r = i >> 7, d = i & 127;
    float v = emb[tok[r] * DIM + d];
    h[i] = f2b(fmaxf(v, 0.f));
}

// eftab[t][d] = sum_k e_token_emb[t][k] * W_fij0[k][d]
__global__ __launch_bounds__(128) void eftab_kernel(const float* __restrict__ etab,
                                                    const float* __restrict__ W,
                                                    float* __restrict__ out) {
    int r = blockIdx.x, d = threadIdx.x;
    float acc = 0.f;
    for (int k = 0; k < DIM; k++)
        acc += etab[r * DIM + k] * W[k * DIM + d];
    out[r * DIM + d] = acc;
}

// ---------------- MFMA node GEMM: grid (400, 3) ----------------
__global__ __launch_bounds__(256, 4) void node_gemm_mfma(
    const ushort_t* __restrict__ h,
    const ushort_t* __restrict__ Wn,
    ushort_t* __restrict__ C0, ushort_t* __restrict__ C1, ushort_t* __restrict__ C2) {
    __shared__ __align__(16) ushort_t wF[16384];
    int tid = threadIdx.x, wv = tid >> 6, lane = tid & 63;
    int r = lane & 15, q = lane >> 4;
    int el = lane >> 2, qq = lane & 3;
    int m = blockIdx.y;
    size_t row = (size_t)blockIdx.x * 64 + 16 * wv;

    // A fragments issued before barrier (overlap W staging)
    const ushort_t* aRow = h + (row + r) * DIM + q * 8;
    bf16x8 a0 = *(const bf16x8*)(aRow);
    bf16x8 a1 = *(const bf16x8*)(aRow + 32);
    bf16x8 a2 = *(const bf16x8*)(aRow + 64);
    bf16x8 a3 = *(const bf16x8*)(aRow + 96);

    {
        const uint4* wg = (const uint4*)(Wn + (size_t)m * NLAYERS * 16384);
        uint4* ws = (uint4*)wF;
        for (int i = tid; i < 2048; i += 256) ws[i] = wg[i];
    }
    __syncthreads();

    f32x4 acc[8] = {};
    const bf16x8* wfrag = (const bf16x8*)wF;
#pragma unroll
    for (int nt = 0; nt < 8; nt++)
        acc[nt] = __builtin_amdgcn_mfma_f32_16x16x32_bf16(a0, wfrag[(0 * 8 + nt) * 64 + lane], acc[nt], 0, 0, 0);
#pragma unroll
    for (int nt = 0; nt < 8; nt++)
        acc[nt] = __builtin_amdgcn_mfma_f32_16x16x32_bf16(a1, wfrag[(1 * 8 + nt) * 64 + lane], acc[nt], 0, 0, 0);
#pragma unroll
    for (int nt = 0; nt < 8; nt++)
        acc[nt] = __builtin_amdgcn_mfma_f32_16x16x32_bf16(a2, wfrag[(2 * 8 + nt) * 64 + lane], acc[nt], 0, 0, 0);
#pragma unroll
    for (int nt = 0; nt < 8; nt++)
        acc[nt] = __builtin_amdgcn_mfma_f32_16x16x32_bf16(a3, wfrag[(3 * 8 + nt) * 64 + lane], acc[nt], 0, 0, 0);
    __syncthreads();

    ushort_t* ss = wF + wv * 16 * STG_S;
#pragma unroll
    for (int nt = 0; nt < 8; nt++)
#pragma unroll
        for (int rg = 0; rg < 4; rg++)
            ss[(q * 4 + rg) * STG_S + nt * 16 + r] = f2b(acc[nt][rg]);

    ushort_t* Cp = (m == 0) ? C0 : (m == 1) ? C1 : C2;
    const uint4* sp = (const uint4*)(ss + el * STG_S + qq * 32);
    uint4* cp = (uint4*)(Cp + (row + el) * DIM + qq * 32);
#pragma unroll
    for (int cc = 0; cc < 4; cc++) cp[cc] = sp[cc];
}

// single-W with bias + relu (final Wf): h bf16 in, fp32 out
__global__ __launch_bounds__(256) void node_gemm1(
    const ushort_t* __restrict__ A, const float* __restrict__ W,
    const float* __restrict__ bias, float* __restrict__ C) {
    __shared__ float As[64 * 128];
    __shared__ uint2 Ws4[128 * 32];
    int tid = threadIdx.x;
    size_t row0 = (size_t)blockIdx.x * 64;
    const uint2* Ag = (const uint2*)(A + row0 * DIM);
    for (int f = tid; f < 64 * 32; f += 256) {
        uint2 v = Ag[f];
        ((float4*)As)[f] = make_float4(
            __uint_as_float(v.x << 16), __uint_as_float(v.x & 0xffff0000u),
            __uint_as_float(v.y << 16), __uint_as_float(v.y & 0xffff0000u));
    }
    const float4* Wg = (const float4*)W;
    for (int i = tid; i < 128 * 32; i += 256) Ws4[i] = pack4(Wg[i]);
    __syncthreads();
    int cq = tid & 31, r0 = (tid >> 5) * 8, c0 = cq * 4;
    float acc[8][4] = {};
    for (int k = 0; k < 128; k++) {
        uint2 wp = Ws4[k * 32 + cq];
        float w0 = __uint_as_float(wp.x << 16);
        float w1 = __uint_as_float(wp.x & 0xffff0000u);
        float w2 = __uint_as_float(wp.y << 16);
        float w3 = __uint_as_float(wp.y & 0xffff0000u);
#pragma unroll
        for (int i = 0; i < 8; i++) {
            float a = As[(r0 + i) * 128 + k];
            acc[i][0] += a * w0; acc[i][1] += a * w1;
            acc[i][2] += a * w2; acc[i][3] += a * w3;
        }
    }
    float b0 = bias[c0], b1 = bias[c0 + 1], b2v = bias[c0 + 2], b3v = bias[c0 + 3];
#pragma unroll
    for (int i = 0; i < 8; i++) {
        *(float4*)&C[(row0 + r0 + i) * DIM + c0] =
            make_float4(fmaxf(acc[i][0] + b0, 0.f), fmaxf(acc[i][1] + b1, 0.f),
                        fmaxf(acc[i][2] + b2v, 0.f), fmaxf(acc[i][3] + b3v, 0.f));
    }
}

// ---------------- MFMA edge GEMM: gathers prefetched behind MFMA phase ----------------
__global__ __launch_bounds__(256, 4) void edge_gemm_mfma(
    ushort_t* __restrict__ e,
    const ushort_t* __restrict__ fni, const ushort_t* __restrict__ fnj,
    const int* __restrict__ psrc, const int* __restrict__ pdst,
    const ushort_t* __restrict__ Wf,
    const float* __restrict__ attn, const float* __restrict__ bias,
    float* __restrict__ score) {
    __shared__ __align__(16) ushort_t wF[16384];

    int tid = threadIdx.x;
    int wv = tid >> 6, lane = tid & 63;
    int r = lane & 15, q = lane >> 4;
    int el = lane >> 2, qq = lane & 3;
    size_t row = (size_t)blockIdx.x * 64 + 16 * wv;
    size_t eid = row + el;

    // edge ids before barrier (tiny, drained with W stage)
    int sv = psrc[eid], dv = pdst[eid];

    // A fragments before barrier (overlap W staging)
    const ushort_t* aRow = e + (row + r) * DIM + q * 8;
    bf16x8 a0 = *(const bf16x8*)(aRow);
    bf16x8 a1 = *(const bf16x8*)(aRow + 32);
    bf16x8 a2 = *(const bf16x8*)(aRow + 64);
    bf16x8 a3 = *(const bf16x8*)(aRow + 96);

    {
        const uint4* wg = (const uint4*)Wf;
        uint4* ws = (uint4*)wF;
        for (int i = tid; i < 2048; i += 256) ws[i] = wg[i];
    }
    __syncthreads();

    // prefetch epilogue gathers NOW — hidden behind the whole MFMA phase,
    // drained by the second barrier exactly when needed
    uint4 niq[4], njq[4];
    {
        const uint4* nip = (const uint4*)(fni + (size_t)sv * DIM + qq * 32);
        const uint4* njp = (const uint4*)(fnj + (size_t)dv * DIM + qq * 32);
#pragma unroll
        for (int cc = 0; cc < 4; cc++) { niq[cc] = nip[cc]; njq[cc] = njp[cc]; }
    }

    f32x4 acc[8] = {};
    const bf16x8* wfrag = (const bf16x8*)wF;
#pragma unroll
    for (int nt = 0; nt < 8; nt++)
        acc[nt] = __builtin_amdgcn_mfma_f32_16x16x32_bf16(a0, wfrag[(0 * 8 + nt) * 64 + lane], acc[nt], 0, 0, 0);
#pragma unroll
    for (int nt = 0; nt < 8; nt++)
        acc[nt] = __builtin_amdgcn_mfma_f32_16x16x32_bf16(a1, wfrag[(1 * 8 + nt) * 64 + lane], acc[nt], 0, 0, 0);
#pragma unroll
    for (int nt = 0; nt < 8; nt++)
        acc[nt] = __builtin_amdgcn_mfma_f32_16x16x32_bf16(a2, wfrag[(2 * 8 + nt) * 64 + lane], acc[nt], 0, 0, 0);
#pragma unroll
    for (int nt = 0; nt < 8; nt++)
        acc[nt] = __builtin_amdgcn_mfma_f32_16x16x32_bf16(a3, wfrag[(3 * 8 + nt) * 64 + lane], acc[nt], 0, 0, 0);
    __syncthreads();

    ushort_t* ss = wF + wv * 16 * STG_S;
#pragma unroll
    for (int nt = 0; nt < 8; nt++)
#pragma unroll
        for (int rg = 0; rg < 4; rg++)
            ss[(q * 4 + rg) * STG_S + nt * 16 + r] = f2b(acc[nt][rg]);

    const uint4* sp = (const uint4*)(ss + el * STG_S + qq * 32);
    uint4 outv[4];
    float p = 0.f;
#pragma unroll
    for (int cc = 0; cc < 4; cc++) {
        uint4 avq = sp[cc];
#pragma unroll
        for (int u = 0; u < 4; u++) {
            unsigned int aw = ((const unsigned int*)&avq)[u];
            unsigned int nw = ((const unsigned int*)&niq[cc])[u];
            unsigned int jw = ((const unsigned int*)&njq[cc])[u];
            int c = qq * 32 + cc * 8 + u * 2;
            float v0 = __uint_as_float(aw << 16) + __uint_as_float(nw << 16) +
                       __uint_as_float(jw << 16) + bias[c];
            float v1 = __uint_as_float(aw & 0xffff0000u) + __uint_as_float(nw & 0xffff0000u) +
                       __uint_as_float(jw & 0xffff0000u) + bias[c + 1];
            v0 = v0 > 0.f ? v0 : 0.01f * v0;
            v1 = v1 > 0.f ? v1 : 0.01f * v1;
            ((unsigned int*)&outv[cc])[u] =
                (unsigned int)f2b(v0) | ((unsigned int)f2b(v1) << 16);
            p += v0 * attn[c] + v1 * attn[c + 1];
        }
    }
    uint4* ep = (uint4*)(e + eid * DIM + qq * 32);
#pragma unroll
    for (int cc = 0; cc < 4; cc++) ep[cc] = outv[cc];
    p += __shfl_xor(p, 1);
    p += __shfl_xor(p, 2);
    if (qq == 0) score[eid] = p;
}

// ---------------- layer-0 edge kernel (permuted order) ----------------
__global__ __launch_bounds__(256) void edge0(
    const int* __restrict__ ptok, const float* __restrict__ eftab,
    const ushort_t* __restrict__ fni, const ushort_t* __restrict__ fnj,
    const int* __restrict__ psrc, const int* __restrict__ pdst,
    const float* __restrict__ attn, const float* __restrict__ bias,
    ushort_t* __restrict__ e, float* __restrict__ score) {
    unsigned int gid = blockIdx.x * 256 + threadIdx.x;
    unsigned int eid = gid >> 5;
    int cq = gid & 31, c0 = cq * 4;
    int tok = ptok[eid];
    int sv = psrc[eid], dv = pdst[eid];
    float4 t = *(const float4*)&eftab[tok * DIM + c0];
    uint2 niw = *(const uint2*)(fni + (size_t)sv * DIM + c0);
    uint2 njw = *(const uint2*)(fnj + (size_t)dv * DIM + c0);
    float ni0 = __uint_as_float(niw.x << 16), ni1 = __uint_as_float(niw.x & 0xffff0000u);
    float ni2 = __uint_as_float(niw.y << 16), ni3 = __uint_as_float(niw.y & 0xffff0000u);
    float nj0 = __uint_as_float(njw.x << 16), nj1 = __uint_as_float(njw.x & 0xffff0000u);
    float nj2 = __uint_as_float(njw.y << 16), nj3 = __uint_as_float(njw.y & 0xffff0000u);
    float v0 = t.x + ni0 + nj0 + bias[c0];
    float v1 = t.y + ni1 + nj1 + bias[c0 + 1];
    float v2 = t.z + ni2 + nj2 + bias[c0 + 2];
    float v3 = t.w + ni3 + nj3 + bias[c0 + 3];
    v0 = v0 > 0.f ? v0 : 0.01f * v0;
    v1 = v1 > 0.f ? v1 : 0.01f * v1;
    v2 = v2 > 0.f ? v2 : 0.01f * v2;
    v3 = v3 > 0.f ? v3 : 0.01f * v3;
    *(uint2*)(e + (size_t)eid * DIM + c0) = pack4(make_float4(v0, v1, v2, v3));
    float p = v0 * attn[c0] + v1 * attn[c0 + 1] + v2 * attn[c0 + 2] + v3 * attn[c0 + 3];
#pragma unroll
    for (int o = 1; o < 32; o <<= 1) p += __shfl_xor(p, o);
    if (cq == 0) score[eid] = p;
}

// ---------------- wave-per-node softmax + aggregation: NO barriers ----------------
__global__ __launch_bounds__(256) void agg_wave(
    const int* __restrict__ off, const int* __restrict__ psrc,
    const float* __restrict__ score, const ushort_t* __restrict__ hs,
    ushort_t* __restrict__ h) {
    int node = blockIdx.x * 4 + (threadIdx.x >> 6);
    int lane = threadIdx.x & 63;
    int b0 = off[node];
    int deg = off[node + 1] - b0;

    float m = -1e30f;
    for (int j = lane; j < deg; j += 64) m = fmaxf(m, score[b0 + j]);
#pragma unroll
    for (int o = 32; o > 0; o >>= 1) m = fmaxf(m, __shfl_xor(m, o));
    float se = 0.f;
    for (int j = lane; j < deg; j += 64) se += __expf(score[b0 + j] - m);
#pragma unroll
    for (int o = 32; o > 0; o >>= 1) se += __shfl_xor(se, o);
    float inv = (deg > 0) ? 1.f / se : 0.f;

    float acc0 = 0.f, acc1 = 0.f;
    for (int base = 0; base < deg; base += 64) {
        int cnt = min(64, deg - base);
        float wgt = 0.f;
        int sidx = 0;
        if (lane < cnt) {
            wgt = __expf(score[b0 + base + lane] - m) * inv;
            sidx = psrc[b0 + base + lane];
        }
        for (int i = 0; i < cnt; i++) {
            float wi = __shfl(wgt, i);
            int si = __shfl(sidx, i);
            unsigned int hv = *(const unsigned int*)(hs + (size_t)si * DIM + lane * 2);
            acc0 += wi * __uint_as_float(hv << 16);
            acc1 += wi * __uint_as_float(hv & 0xffff0000u);
        }
    }
    unsigned int outp = (unsigned int)f2b(fmaxf(acc0, 0.f)) |
                        ((unsigned int)f2b(fmaxf(acc1, 0.f)) << 16);
    *(unsigned int*)(h + (size_t)node * DIM + lane * 2) = outp;
}

// ---------------- sort each node's 128 features ascending ----------------
__global__ __launch_bounds__(128) void sort_rows(const float* __restrict__ h2,
                                                 float* __restrict__ hsort,
                                                 float* __restrict__ maxval) {
    __shared__ float buf[128];
    int n = blockIdx.x, t = threadIdx.x;
    buf[t] = h2[(size_t)n * DIM + t];
    __syncthreads();
    for (int k = 2; k <= 128; k <<= 1) {
        for (int j = k >> 1; j > 0; j >>= 1) {
            int ixj = t ^ j;
            float a = buf[t], b = buf[ixj];
            __syncthreads();
            bool up = ((t & k) == 0);
            float mn = fminf(a, b), mx = fmaxf(a, b);
            buf[t] = up ? ((t < ixj) ? mn : mx) : ((t < ixj) ? mx : mn);
            __syncthreads();
        }
    }
    hsort[(size_t)n * DIM + t] = buf[t];
    if (t == 127) maxval[n] = buf[127];
}

// ---------------- per-graph top-k + gather pooled rows ----------------
__global__ __launch_bounds__(256) void topk_pool(const float* __restrict__ maxval,
                                                 const float* __restrict__ hsort,
                                                 float* __restrict__ pooled) {
    __shared__ float v[256];
    __shared__ int id[256];
    int b = blockIdx.x, t = threadIdx.x;
    v[t] = (t < NPG) ? maxval[b * NPG + t] : -1e30f;
    id[t] = t;
    __syncthreads();
    for (int k = 2; k <= 256; k <<= 1) {
        for (int j = k >> 1; j > 0; j >>= 1) {
            int ixj = t ^ j;
            float va = v[t], vb = v[ixj];
            int ia = id[t], ib = id[ixj];
            __syncthreads();
            bool dirDesc = ((t & k) == 0);
            bool cmp = (va > vb) || (va == vb && ia < ib);
            bool takeMine = ((t < ixj) == (dirDesc == cmp));
            v[t] = takeMine ? va : vb;
            id[t] = takeMine ? ia : ib;
            __syncthreads();
        }
    }
    for (int i = t; i < KPOOL * DIM; i += 256) {
        int kk = i >> 7, d = i & 127;
        pooled[((size_t)b * KPOOL + kk) * DIM + d] = hsort[((size_t)b * NPG + id[kk]) * DIM + d];
    }
}

// ---------------- ft split-K ----------------
__global__ __launch_bounds__(256) void ft_partial(
    const float* __restrict__ pooled, const float* __restrict__ W3,
    float* __restrict__ part) {
    __shared__ float ps[512];
    __shared__ float red[256];
    int b = blockIdx.x, s = blockIdx.y;
    int t = threadIdx.x;
    int d = t & 127, half = t >> 7;
    for (int i = t; i < 512; i += 256) ps[i] = pooled[(size_t)b * 4096 + s * 512 + i];
    __syncthreads();
    float acc = 0.f;
    const float* Wp = W3 + (size_t)(s * 512 + half * 256) * DIM + d;
    const float* pp = ps + half * 256;
#pragma unroll 4
    for (int kk = 0; kk < 256; kk++) acc += pp[kk] * Wp[(size_t)kk * DIM];
    red[t] = acc;
    __syncthreads();
    if (t < 128) part[((size_t)b * 8 + s) * DIM + t] = red[t] + red[t + 128];
}

__global__ __launch_bounds__(128) void ft_reduce(
    const float* __restrict__ part, const float* __restrict__ al3,
    const float* __restrict__ ar3, float* __restrict__ ft,
    float* __restrict__ sl, float* __restrict__ sr) {
    __shared__ float r1[128], r2[128];
    int b = blockIdx.x, d = threadIdx.x;
    float acc = 0.f;
#pragma unroll
    for (int s = 0; s < 8; s++) acc += part[((size_t)b * 8 + s) * DIM + d];
    ft[b * DIM + d] = acc;
    r1[d] = acc * al3[d];
    r2[d] = acc * ar3[d];
    __syncthreads();
    for (int s = 64; s > 0; s >>= 1) {
        if (d < s) { r1[d] += r1[d + s]; r2[d] += r2[d + s]; }
        __syncthreads();
    }
    if (d == 0) { sl[b] = r1[0]; sr[b] = r2[0]; }
}

// ---------------- final-graph GAT ----------------
__global__ __launch_bounds__(128) void fg_kernel(
    const int* __restrict__ fg_src, const int* __restrict__ fg_dst,
    const float* __restrict__ sl, const float* __restrict__ sr,
    const float* __restrict__ ft, const float* __restrict__ b3,
    float* __restrict__ g) {
    __shared__ int list[EFE];
    __shared__ float wgt[EFE];
    __shared__ float red[128];
    __shared__ int cnt;
    int b = blockIdx.x, t = threadIdx.x;
    if (t == 0) cnt = 0;
    __syncthreads();
    for (int e = t; e < EFE; e += 128)
        if (fg_dst[e] == b) { int p = atomicAdd(&cnt, 1); list[p] = e; }
    __syncthreads();
    int deg = cnt;
    float srb = sr[b];
    float m = -1e30f;
    for (int j = t; j < deg; j += 128) {
        float s = sl[fg_src[list[j]]] + srb;
        s = s > 0.f ? s : 0.2f * s;
        m = fmaxf(m, s);
    }
    red[t] = m;
    __syncthreads();
    for (int s = 64; s > 0; s >>= 1) { if (t < s) red[t] = fmaxf(red[t], red[t + s]); __syncthreads(); }
    m = red[0];
    __syncthreads();
    float se = 0.f;
    for (int j = t; j < deg; j += 128) {
        float s = sl[fg_src[list[j]]] + srb;
        s = s > 0.f ? s : 0.2f * s;
        se += __expf(s - m);
    }
    red[t] = se;
    __syncthreads();
    for (int s = 64; s > 0; s >>= 1) { if (t < s) red[t] += red[t + s]; __syncthreads(); }
    float inv = (deg > 0) ? 1.f / red[0] : 0.f;
    __syncthreads();
    for (int j = t; j < deg; j += 128) {
        float s = sl[fg_src[list[j]]] + srb;
        s = s > 0.f ? s : 0.2f * s;
        wgt[j] = __expf(s - m) * inv;
    }
    __syncthreads();
    float acc = 0.f;
    for (int j = 0; j < deg; j++) acc += wgt[j] * ft[(size_t)fg_src[list[j]] * DIM + t];
    g[b * DIM + t] = fmaxf(acc + b3[t], 0.f);
}

// ---------------- g2 = relu(g @ Wl + bl) ----------------
__global__ __launch_bounds__(128) void gl_kernel(const float* __restrict__ g,
                                                 const float* __restrict__ Wl,
                                                 const float* __restrict__ bl,
                                                 float* __restrict__ g2) {
    __shared__ float gs[128];
    int b = blockIdx.x, d = threadIdx.x;
    gs[d] = g[b * DIM + d];
    __syncthreads();
    float acc = 0.f;
    for (int k = 0; k < 128; k++) acc += gs[k] * Wl[k * DIM + d];
    g2[b * DIM + d] = fmaxf(acc + bl[d], 0.f);
}

// ---------------- out = g2 @ Wc + bc ----------------
__global__ __launch_bounds__(256) void out_kernel(const float* __restrict__ g2,
                                                  const float* __restrict__ Wc,
                                                  const float* __restrict__ bc,
                                                  float* __restrict__ out) {
    int i = threadIdx.x;
    int b = i >> 1, j = i & 1;
    float acc = bc[j];
    for (int k = 0; k < 128; k++) acc += g2[b * DIM + k] * Wc[k * 2 + j];
    out[b * 2 + j] = acc;
}

extern "C" void kernel_launch(void* const* d_in, const int* in_sizes, int n_in,
                              void* d_out, int out_size, void* d_ws, size_t ws_size,
                              hipStream_t stream) {
    const int* tokens_h = (const int*)d_in[0];
    const int* tokens_e = (const int*)d_in[1];
    const int* src = (const int*)d_in[2];
    const int* dst = (const int*)d_in[3];
    const int* fg_src = (const int*)d_in[4];
    const int* fg_dst = (const int*)d_in[5];
    const float* token_emb = (const float*)d_in[6];
    const float* e_token_emb = (const float*)d_in[7];
    const float* W_ni = (const float*)d_in[8];
    const float* W_nj = (const float*)d_in[9];
    const float* W_fij = (const float*)d_in[10];
    const float* W_node = (const float*)d_in[11];
    const float* attn_e = (const float*)d_in[12];
    const float* bias_e = (const float*)d_in[13];
    const float* Wf = (const float*)d_in[14];
    const float* bf_ = (const float*)d_in[15];
    const float* W3 = (const float*)d_in[16];
    const float* al3 = (const float*)d_in[17];
    const float* ar3 = (const float*)d_in[18];
    const float* b3 = (const float*)d_in[19];
    const float* Wl = (const float*)d_in[20];
    const float* bl = (const float*)d_in[21];
    const float* Wc = (const float*)d_in[22];
    const float* bc = (const float*)d_in[23];
    float* out = (float*)d_out;

    char* w = (char*)d_ws;
    auto alloc = [&](size_t b) -> char* {
        char* p = w;
        w += (b + 255) & ~(size_t)255;
        return p;
    };
    ushort_t* h = (ushort_t*)alloc((size_t)N_NODES * DIM * 2);
    ushort_t* fni = (ushort_t*)alloc((size_t)N_NODES * DIM * 2);
    ushort_t* fnj = (ushort_t*)alloc((size_t)N_NODES * DIM * 2);
    ushort_t* hs = (ushort_t*)alloc((size_t)N_NODES * DIM * 2);
    ushort_t* e = (ushort_t*)alloc((size_t)N_EDGES * DIM * 2);
    float* score = (float*)alloc((size_t)N_EDGES * 4);
    int* deg = (int*)alloc((size_t)N_NODES * 4);
    int* off = (int*)alloc((size_t)(N_NODES + 1) * 4);
    int* cursor = (int*)alloc((size_t)N_NODES * 4);
    int* bsum = (int*)alloc(64 * 4);
    int* psrc = (int*)alloc((size_t)N_EDGES * 4);
    int* pdst = (int*)alloc((size_t)N_EDGES * 4);
    int* ptok = (int*)alloc((size_t)N_EDGES * 4);
    float* eftab = (float*)alloc(100 * DIM * 4);
    float* maxval = (float*)alloc((size_t)N_NODES * 4);
    float* pooled = (float*)alloc((size_t)BGR * KPOOL * DIM * 4);
    float* ft = (float*)alloc(BGR * DIM * 4);
    float* part = (float*)alloc((size_t)BGR * 8 * DIM * 4);
    float* sl = (float*)alloc(BGR * 4);
    float* sr = (float*)alloc(BGR * 4);
    float* g = (float*)alloc(BGR * DIM * 4);
    float* g2 = (float*)alloc(BGR * DIM * 4);
    ushort_t* Wf7 = (ushort_t*)alloc((size_t)NLAYERS * DIM * DIM * 2);
    ushort_t* Wn = (ushort_t*)alloc((size_t)3 * NLAYERS * DIM * DIM * 2);
    float* h2 = (float*)e;
    float* hsort = (float*)((char*)e + (size_t)16 * 1024 * 1024);

    // weight prep
    wfprep<<<(NLAYERS * DIM * DIM) / 256, 256, 0, stream>>>(W_fij, Wf7);
    wnprep<<<(3 * NLAYERS * DIM * DIM) / 256, 256, 0, stream>>>(W_ni, W_nj, W_node, Wn);

    // CSR build + edge permutation (dst-sorted order), hierarchical scan
    zero_deg<<<(N_NODES + 255) / 256, 256, 0, stream>>>(deg, N_NODES);
    count_deg<<<N_EDGES / 256, 256, 0, stream>>>(dst, deg, N_EDGES);
    scan_local<<<(N_NODES + 1023) / 1024, 1024, 0, stream>>>(deg, off, bsum, N_NODES);
    scan_bsum<<<1, 32, 0, stream>>>(bsum, (N_NODES + 1023) / 1024);
    scan_add<<<(N_NODES + 255) / 256, 256, 0, stream>>>(off, bsum, cursor, N_NODES, N_EDGES);
    scatter_perm<<<N_EDGES / 256, 256, 0, stream>>>(src, dst, tokens_e, cursor,
                                                    psrc, pdst, ptok, N_EDGES);

    init_h<<<(N_NODES * DIM) / 256, 256, 0, stream>>>(tokens_h, token_emb, h);
    eftab_kernel<<<100, 128, 0, stream>>>(e_token_emb, W_fij, eftab);

    for (int l = 0; l < NLAYERS; l++) {
        node_gemm_mfma<<<dim3(N_NODES / 64, 3), 256, 0, stream>>>(
            h, Wn + l * 16384, fni, fnj, hs);
        if (l == 0) {
            edge0<<<(N_EDGES * 32) / 256, 256, 0, stream>>>(
                ptok, eftab, fni, fnj, psrc, pdst, attn_e, bias_e, e, score);
        } else {
            edge_gemm_mfma<<<N_EDGES / 64, 256, 0, stream>>>(
                e, fni, fnj, psrc, pdst, Wf7 + l * DIM * DIM,
                attn_e + l * DIM, bias_e + l * DIM, score);
        }
        agg_wave<<<N_NODES / 4, 256, 0, stream>>>(off, psrc, score, hs, h);
    }

    node_gemm1<<<N_NODES / 64, 256, 0, stream>>>(h, Wf, bf_, h2);
    sort_rows<<<N_NODES, 128, 0, stream>>>(h2, hsort, maxval);
    topk_pool<<<BGR, 256, 0, stream>>>(maxval, hsort, pooled);
    ft_partial<<<dim3(BGR, 8), 256, 0, stream>>>(pooled, W3, part);
    ft_reduce<<<BGR, 128, 0, stream>>>(part, al3, ar3, ft, sl, sr);
    fg_kernel<<<BGR, 128, 0, stream>>>(fg_src, fg_dst, sl, sr, ft, b3, g);
    gl_kernel<<<BGR, 128, 0, stream>>>(g, Wl, bl, g2);
    out_kernel<<<1, 256, 0, stream>>>(g2, Wc, bc, out);
}